// Round 1
// baseline (1565.025 us; speedup 1.0000x reference)
//
#include <hip/hip_runtime.h>

#define NNODE_MAX 50000
#define IN_DIM 256
#define OUT_DIM 128
#define N_CLS 40

// ---------------------------------------------------------------------------
// Kernel 1: degrees via atomics. deg_out[src[e]]++, deg_in[dst[e]]++
// ---------------------------------------------------------------------------
__global__ __launch_bounds__(256) void deg_kernel(
    const int* __restrict__ src, const int* __restrict__ dst,
    float* __restrict__ deg_out, float* __restrict__ deg_in, int ne)
{
    int i = blockIdx.x * blockDim.x + threadIdx.x;
    int stride = gridDim.x * blockDim.x;
    for (; i < ne; i += stride) {
        atomicAdd(&deg_out[src[i]], 1.0f);
        atomicAdd(&deg_in[dst[i]], 1.0f);
    }
}

// ---------------------------------------------------------------------------
// Kernel 2: h = (emb[nodes] * rsqrt(max(deg_out,1))) @ W
// M=50000, K=256, N=128 fp32.  64-row tile, 256 threads, each thread 8x4 acc.
// ---------------------------------------------------------------------------
__global__ __launch_bounds__(256) void gemm1_kernel(
    const int* __restrict__ nodes, const float* __restrict__ emb,
    const float* __restrict__ W, const float* __restrict__ deg_out,
    float* __restrict__ h, int n)
{
    __shared__ float As[8][64];     // k-major: As[k][row]
    __shared__ float Ws[8][128];    // Ws[k][col]
    __shared__ int   snode[64];
    __shared__ float sscale[64];

    const int tid = threadIdx.x;
    const int m0  = blockIdx.x * 64;

    if (tid < 64) {
        int gr = m0 + tid;
        if (gr < n) {
            snode[tid]  = nodes[gr];
            sscale[tid] = rsqrtf(fmaxf(deg_out[gr], 1.0f));
        } else {
            snode[tid]  = 0;
            sscale[tid] = 0.0f;
        }
    }
    __syncthreads();

    const int tcol = tid & 31;   // 32 col-groups of 4
    const int trow = tid >> 5;   // 8 row-groups of 8

    float acc[8][4];
#pragma unroll
    for (int i = 0; i < 8; i++)
#pragma unroll
        for (int j = 0; j < 4; j++) acc[i][j] = 0.0f;

    for (int k0 = 0; k0 < IN_DIM; k0 += 8) {
        // A tile: 512 elems, 2 per thread (k-major so frag reads vectorize)
#pragma unroll
        for (int i = 0; i < 2; i++) {
            int idx = tid + i * 256;
            int k = idx >> 6, r = idx & 63;
            As[k][r] = emb[(size_t)snode[r] * IN_DIM + k0 + k] * sscale[r];
        }
        // W tile: 1024 elems, 4 per thread, coalesced
#pragma unroll
        for (int i = 0; i < 4; i++) {
            int idx = tid + i * 256;
            int kk = idx >> 7, c = idx & 127;
            Ws[kk][c] = W[(size_t)(k0 + kk) * OUT_DIM + c];
        }
        __syncthreads();

#pragma unroll
        for (int k = 0; k < 8; k++) {
            float a[8], w[4];
#pragma unroll
            for (int i = 0; i < 8; i++) a[i] = As[k][trow * 8 + i];
#pragma unroll
            for (int j = 0; j < 4; j++) w[j] = Ws[k][tcol * 4 + j];
#pragma unroll
            for (int i = 0; i < 8; i++)
#pragma unroll
                for (int j = 0; j < 4; j++) acc[i][j] += a[i] * w[j];
        }
        __syncthreads();
    }

#pragma unroll
    for (int i = 0; i < 8; i++) {
        int gr = m0 + trow * 8 + i;
        if (gr < n) {
            float4 v = make_float4(acc[i][0], acc[i][1], acc[i][2], acc[i][3]);
            *(float4*)&h[(size_t)gr * OUT_DIM + tcol * 4] = v;
        }
    }
}

// ---------------------------------------------------------------------------
// Kernel 3: SpMM  agg[dst[e]] += h[src[e]]  (float atomics, 32 lanes/edge)
// agg lives directly in d_out's feat_out region (pre-zeroed).
// ---------------------------------------------------------------------------
__global__ __launch_bounds__(256) void spmm_kernel(
    const int* __restrict__ src, const int* __restrict__ dst,
    const float* __restrict__ h, float* __restrict__ agg, int ne)
{
    size_t tid = (size_t)blockIdx.x * 256 + threadIdx.x;
    int e = (int)(tid >> 5);
    if (e >= ne) return;
    int c = (int)(tid & 31) * 4;
    int s = src[e], d = dst[e];
    const float4 v = *(const float4*)&h[(size_t)s * OUT_DIM + c];
    float* ap = &agg[(size_t)d * OUT_DIM + c];
    atomicAdd(ap + 0, v.x);
    atomicAdd(ap + 1, v.y);
    atomicAdd(ap + 2, v.z);
    atomicAdd(ap + 3, v.w);
}

// ---------------------------------------------------------------------------
// Kernel 4: feat_out = agg * rsqrt(max(deg_in,1)) + b  (in-place in d_out),
//           logits  = feat_out @ mlp_w + mlp_b
// One row per wave; mlp_w staged in LDS.
// ---------------------------------------------------------------------------
__global__ __launch_bounds__(256) void finalize_kernel(
    const float* __restrict__ deg_in, const float* __restrict__ bias,
    const float* __restrict__ mlp_w, const float* __restrict__ mlp_b,
    float* __restrict__ out_feat, float* __restrict__ out_logits, int n)
{
    __shared__ float s_mlpw[OUT_DIM * N_CLS]; // 20 KB
    __shared__ float s_fo[4][OUT_DIM];
    __shared__ float s_mlpb[N_CLS];
    __shared__ float s_bias[OUT_DIM];

    const int tid = threadIdx.x;
    for (int i = tid; i < OUT_DIM * N_CLS; i += 256) s_mlpw[i] = mlp_w[i];
    if (tid < N_CLS)  s_mlpb[tid] = mlp_b[tid];
    if (tid < OUT_DIM) s_bias[tid] = bias[tid];
    __syncthreads();

    const int wid = tid >> 6, lane = tid & 63;
    for (int row = blockIdx.x * 4 + wid; row < n; row += gridDim.x * 4) {
        float nd = rsqrtf(fmaxf(deg_in[row], 1.0f));
        float a0 = out_feat[(size_t)row * OUT_DIM + lane];
        float a1 = out_feat[(size_t)row * OUT_DIM + 64 + lane];
        float f0 = a0 * nd + s_bias[lane];
        float f1 = a1 * nd + s_bias[64 + lane];
        out_feat[(size_t)row * OUT_DIM + lane]      = f0;
        out_feat[(size_t)row * OUT_DIM + 64 + lane] = f1;
        s_fo[wid][lane]      = f0;
        s_fo[wid][64 + lane] = f1;
        // wave-synchronous LDS broadcast: force the writes to land before reads
        asm volatile("s_waitcnt lgkmcnt(0)" ::: "memory");

        if (lane < N_CLS) {
            float acc = s_mlpb[lane];
#pragma unroll 8
            for (int k = 0; k < OUT_DIM; k++)
                acc += s_fo[wid][k] * s_mlpw[k * N_CLS + lane];
            out_logits[(size_t)row * N_CLS + lane] = acc;
        }
    }
}

// ---------------------------------------------------------------------------
extern "C" void kernel_launch(void* const* d_in, const int* in_sizes, int n_in,
                              void* d_out, int out_size, void* d_ws, size_t ws_size,
                              hipStream_t stream) {
    const int*   nodes = (const int*)d_in[0];
    const int*   src   = (const int*)d_in[1];
    const int*   dst   = (const int*)d_in[2];
    const float* emb   = (const float*)d_in[3];
    const float* W     = (const float*)d_in[4];
    const float* b     = (const float*)d_in[5];
    const float* mlp_w = (const float*)d_in[6];
    const float* mlp_b = (const float*)d_in[7];

    const int n  = in_sizes[0];   // 50000
    const int ne = in_sizes[1];   // 800000

    // workspace layout (floats): deg_out[n] | deg_in[n] | h[n*128]
    float* ws       = (float*)d_ws;
    float* deg_out  = ws;
    float* deg_in   = ws + n;
    float* h        = ws + 2 * (size_t)n;

    float* out_feat   = (float*)d_out;                       // n*128
    float* out_logits = out_feat + (size_t)n * OUT_DIM;      // n*40

    // zero degree counters and the atomic accumulator (= out_feat region)
    hipMemsetAsync(d_ws, 0, (size_t)2 * n * sizeof(float), stream);
    hipMemsetAsync(out_feat, 0, (size_t)n * OUT_DIM * sizeof(float), stream);

    deg_kernel<<<1024, 256, 0, stream>>>(src, dst, deg_out, deg_in, ne);

    gemm1_kernel<<<(n + 63) / 64, 256, 0, stream>>>(nodes, emb, W, deg_out, h, n);

    long long spmm_threads = (long long)ne * 32;
    spmm_kernel<<<(int)((spmm_threads + 255) / 256), 256, 0, stream>>>(
        src, dst, h, out_feat, ne);

    finalize_kernel<<<2048, 256, 0, stream>>>(
        deg_in, b, mlp_w, mlp_b, out_feat, out_logits, n);
}

// Round 2
// 360.645 us; speedup vs baseline: 4.3395x; 4.3395x over previous
//
#include <hip/hip_runtime.h>

#define IN_DIM 256
#define OUT_DIM 128
#define N_CLS 40

// ---------------------------------------------------------------------------
// Kernel 1: int histograms. cnt_out[src[e]]++, cnt_in[dst[e]]++
// ---------------------------------------------------------------------------
__global__ __launch_bounds__(256) void deg_kernel(
    const int* __restrict__ src, const int* __restrict__ dst,
    int* __restrict__ cnt_out, int* __restrict__ cnt_in, int ne)
{
    int i = blockIdx.x * blockDim.x + threadIdx.x;
    int stride = gridDim.x * blockDim.x;
    for (; i < ne; i += stride) {
        atomicAdd(&cnt_out[src[i]], 1);
        atomicAdd(&cnt_in[dst[i]], 1);
    }
}

// ---------------------------------------------------------------------------
// Kernel 2: single-block exclusive scan of cnt_in -> row_start[n+1], cursor[n]
// 1024 threads, wave-shuffle scan + cross-wave LDS, ~49 chunks.
// ---------------------------------------------------------------------------
__global__ __launch_bounds__(1024) void scan_kernel(
    const int* __restrict__ cnt, int* __restrict__ row_start,
    int* __restrict__ cursor, int n)
{
    __shared__ int wsum[16];
    __shared__ int carry_s;
    const int tid = threadIdx.x;
    const int lane = tid & 63, wid = tid >> 6;
    if (tid == 0) carry_s = 0;
    __syncthreads();

    for (int chunk = 0; chunk < n; chunk += 1024) {
        int idx = chunk + tid;
        int v = (idx < n) ? cnt[idx] : 0;
        int incl = v;
#pragma unroll
        for (int off = 1; off < 64; off <<= 1) {
            int t = __shfl_up(incl, (unsigned)off, 64);
            if (lane >= off) incl += t;
        }
        if (lane == 63) wsum[wid] = incl;
        __syncthreads();
        int woff = 0;
        for (int w = 0; w < wid; ++w) woff += wsum[w];  // broadcast reads
        int carry = carry_s;
        int excl = carry + woff + incl - v;
        if (idx < n) { row_start[idx] = excl; cursor[idx] = excl; }
        __syncthreads();                 // all reads of carry_s/wsum done
        if (tid == 1023) carry_s = carry + woff + incl;
        __syncthreads();
    }
    if (tid == 0) row_start[n] = carry_s;
}

// ---------------------------------------------------------------------------
// Kernel 3: scatter edges into dst-sorted CSR. csr_src[pos] = src[e]
// ---------------------------------------------------------------------------
__global__ __launch_bounds__(256) void scatter_kernel(
    const int* __restrict__ src, const int* __restrict__ dst,
    int* __restrict__ cursor, int* __restrict__ csr_src, int ne)
{
    int i = blockIdx.x * blockDim.x + threadIdx.x;
    int stride = gridDim.x * blockDim.x;
    for (; i < ne; i += stride) {
        int pos = atomicAdd(&cursor[dst[i]], 1);
        csr_src[pos] = src[i];
    }
}

// ---------------------------------------------------------------------------
// Kernel 4: h = (emb[nodes] * rsqrt(max(cnt_out,1))) @ W   (fp32 vector GEMM)
// ---------------------------------------------------------------------------
__global__ __launch_bounds__(256) void gemm1_kernel(
    const int* __restrict__ nodes, const float* __restrict__ emb,
    const float* __restrict__ W, const int* __restrict__ cnt_out,
    float* __restrict__ h, int n)
{
    __shared__ float As[8][64];     // k-major
    __shared__ float Ws[8][128];
    __shared__ int   snode[64];
    __shared__ float sscale[64];

    const int tid = threadIdx.x;
    const int m0  = blockIdx.x * 64;

    if (tid < 64) {
        int gr = m0 + tid;
        if (gr < n) {
            snode[tid]  = nodes[gr];
            sscale[tid] = rsqrtf(fmaxf((float)cnt_out[gr], 1.0f));
        } else {
            snode[tid]  = 0;
            sscale[tid] = 0.0f;
        }
    }
    __syncthreads();

    const int tcol = tid & 31;
    const int trow = tid >> 5;

    float acc[8][4];
#pragma unroll
    for (int i = 0; i < 8; i++)
#pragma unroll
        for (int j = 0; j < 4; j++) acc[i][j] = 0.0f;

    for (int k0 = 0; k0 < IN_DIM; k0 += 8) {
#pragma unroll
        for (int i = 0; i < 2; i++) {
            int idx = tid + i * 256;
            int k = idx >> 6, r = idx & 63;
            As[k][r] = emb[(size_t)snode[r] * IN_DIM + k0 + k] * sscale[r];
        }
#pragma unroll
        for (int i = 0; i < 4; i++) {
            int idx = tid + i * 256;
            int kk = idx >> 7, c = idx & 127;
            Ws[kk][c] = W[(size_t)(k0 + kk) * OUT_DIM + c];
        }
        __syncthreads();

#pragma unroll
        for (int k = 0; k < 8; k++) {
            float a[8], w[4];
#pragma unroll
            for (int i = 0; i < 8; i++) a[i] = As[k][trow * 8 + i];
#pragma unroll
            for (int j = 0; j < 4; j++) w[j] = Ws[k][tcol * 4 + j];
#pragma unroll
            for (int i = 0; i < 8; i++)
#pragma unroll
                for (int j = 0; j < 4; j++) acc[i][j] += a[i] * w[j];
        }
        __syncthreads();
    }

#pragma unroll
    for (int i = 0; i < 8; i++) {
        int gr = m0 + trow * 8 + i;
        if (gr < n) {
            float4 v = make_float4(acc[i][0], acc[i][1], acc[i][2], acc[i][3]);
            *(float4*)&h[(size_t)gr * OUT_DIM + tcol * 4] = v;
        }
    }
}

// ---------------------------------------------------------------------------
// Kernel 5: fused CSR-SpMM + norm + bias + MLP.
// One wave per dst row: gather-sum h[csr_src[j]] (float2/lane), then
// feat = acc*rsqrt(deg)+b  -> d_out, logits = feat@mlp_w+mlp_b -> d_out.
// ---------------------------------------------------------------------------
__global__ __launch_bounds__(256) void spmm_csr_kernel(
    const int* __restrict__ row_start, const int* __restrict__ row_end,
    const int* __restrict__ csr_src, const float* __restrict__ h,
    const float* __restrict__ bias, const float* __restrict__ mlp_w,
    const float* __restrict__ mlp_b,
    float* __restrict__ out_feat, float* __restrict__ out_logits, int n)
{
    __shared__ float s_mlpw[OUT_DIM * N_CLS]; // 20 KB
    __shared__ float s_fo[4][OUT_DIM];
    __shared__ float s_mlpb[N_CLS];
    __shared__ float s_bias[OUT_DIM];

    const int tid = threadIdx.x;
    for (int i = tid; i < OUT_DIM * N_CLS; i += 256) s_mlpw[i] = mlp_w[i];
    if (tid < N_CLS)   s_mlpb[tid] = mlp_b[tid];
    if (tid < OUT_DIM) s_bias[tid] = bias[tid];
    __syncthreads();

    const int wid = tid >> 6, lane = tid & 63;
    const int c = lane * 2;

    for (int row = blockIdx.x * 4 + wid; row < n; row += gridDim.x * 4) {
        const int rs = row_start[row];
        const int re = row_end[row];        // == row_start[row+1] after scatter

        float2 acc0 = make_float2(0.f, 0.f);
        float2 acc1 = make_float2(0.f, 0.f);
        int j = rs;
        for (; j + 1 < re; j += 2) {
            int s0 = csr_src[j];
            int s1 = csr_src[j + 1];
            float2 v0 = *(const float2*)&h[(size_t)s0 * OUT_DIM + c];
            float2 v1 = *(const float2*)&h[(size_t)s1 * OUT_DIM + c];
            acc0.x += v0.x; acc0.y += v0.y;
            acc1.x += v1.x; acc1.y += v1.y;
        }
        if (j < re) {
            int s0 = csr_src[j];
            float2 v0 = *(const float2*)&h[(size_t)s0 * OUT_DIM + c];
            acc0.x += v0.x; acc0.y += v0.y;
        }

        const float nd = rsqrtf(fmaxf((float)(re - rs), 1.0f));
        const float f0 = (acc0.x + acc1.x) * nd + s_bias[c];
        const float f1 = (acc0.y + acc1.y) * nd + s_bias[c + 1];
        *(float2*)&out_feat[(size_t)row * OUT_DIM + c] = make_float2(f0, f1);

        s_fo[wid][c]     = f0;
        s_fo[wid][c + 1] = f1;
        asm volatile("s_waitcnt lgkmcnt(0)" ::: "memory"); // wave-sync LDS

        if (lane < N_CLS) {
            float acc = s_mlpb[lane];
#pragma unroll 8
            for (int k = 0; k < OUT_DIM; k++)
                acc += s_fo[wid][k] * s_mlpw[k * N_CLS + lane];
            out_logits[(size_t)row * N_CLS + lane] = acc;
        }
    }
}

// ---------------------------------------------------------------------------
extern "C" void kernel_launch(void* const* d_in, const int* in_sizes, int n_in,
                              void* d_out, int out_size, void* d_ws, size_t ws_size,
                              hipStream_t stream) {
    const int*   nodes = (const int*)d_in[0];
    const int*   src   = (const int*)d_in[1];
    const int*   dst   = (const int*)d_in[2];
    const float* emb   = (const float*)d_in[3];
    const float* W     = (const float*)d_in[4];
    const float* b     = (const float*)d_in[5];
    const float* mlp_w = (const float*)d_in[6];
    const float* mlp_b = (const float*)d_in[7];

    const int n  = in_sizes[0];   // 50000
    const int ne = in_sizes[1];   // 800000

    // workspace layout: cnt_out[n] | cnt_in[n] | row_start[n+1] | cursor[n]
    //                   | csr_src[ne] | (16B-aligned) h[n*128]
    int* cnt_out   = (int*)d_ws;
    int* cnt_in    = cnt_out + n;
    int* row_start = cnt_in + n;          // n+1
    int* cursor    = row_start + n + 1;
    int* csr_src   = cursor + n;
    size_t int_bytes = ((size_t)(4 * n + 1) + (size_t)ne) * sizeof(int);
    size_t h_off = (int_bytes + 15) & ~(size_t)15;
    float* h = (float*)((char*)d_ws + h_off);

    float* out_feat   = (float*)d_out;                    // n*128
    float* out_logits = out_feat + (size_t)n * OUT_DIM;   // n*40

    hipMemsetAsync(d_ws, 0, (size_t)2 * n * sizeof(int), stream); // cnt_out+cnt_in

    deg_kernel<<<1024, 256, 0, stream>>>(src, dst, cnt_out, cnt_in, ne);

    scan_kernel<<<1, 1024, 0, stream>>>(cnt_in, row_start, cursor, n);

    scatter_kernel<<<1024, 256, 0, stream>>>(src, dst, cursor, csr_src, ne);

    gemm1_kernel<<<(n + 63) / 64, 256, 0, stream>>>(nodes, emb, W, cnt_out, h, n);

    // after scatter, cursor[row] == row_start[row+1] -> use as row_end
    spmm_csr_kernel<<<(n + 3) / 4, 256, 0, stream>>>(
        row_start, cursor, csr_src, h, b, mlp_w, mlp_b,
        out_feat, out_logits, n);
}

// Round 3
// 274.526 us; speedup vs baseline: 5.7008x; 1.3137x over previous
//
#include <hip/hip_runtime.h>

#define IN_DIM 256
#define OUT_DIM 128
#define N_CLS 40

typedef __attribute__((ext_vector_type(8))) short short8;
typedef __attribute__((ext_vector_type(4))) float floatx4;

static __device__ __forceinline__ unsigned short f2bf(float f) {
    union { float f; unsigned u; } v; v.f = f;
    unsigned r = v.u + 0x7FFF + ((v.u >> 16) & 1);
    return (unsigned short)(r >> 16);
}

// ---------------------------------------------------------------------------
// Kernel 1: int histograms. cnt_out[src[e]]++, cnt_in[dst[e]]++
// ---------------------------------------------------------------------------
__global__ __launch_bounds__(256) void deg_kernel(
    const int* __restrict__ src, const int* __restrict__ dst,
    int* __restrict__ cnt_out, int* __restrict__ cnt_in, int ne)
{
    int i = blockIdx.x * blockDim.x + threadIdx.x;
    int stride = gridDim.x * blockDim.x;
    for (; i < ne; i += stride) {
        atomicAdd(&cnt_out[src[i]], 1);
        atomicAdd(&cnt_in[dst[i]], 1);
    }
}

// ---------------------------------------------------------------------------
// Kernel 2: single-block exclusive scan of cnt_in -> row_start[n+1], cursor[n]
// ---------------------------------------------------------------------------
__global__ __launch_bounds__(1024) void scan_kernel(
    const int* __restrict__ cnt, int* __restrict__ row_start,
    int* __restrict__ cursor, int n)
{
    __shared__ int wsum[16];
    __shared__ int carry_s;
    const int tid = threadIdx.x;
    const int lane = tid & 63, wid = tid >> 6;
    if (tid == 0) carry_s = 0;
    __syncthreads();

    for (int chunk = 0; chunk < n; chunk += 1024) {
        int idx = chunk + tid;
        int v = (idx < n) ? cnt[idx] : 0;
        int incl = v;
#pragma unroll
        for (int off = 1; off < 64; off <<= 1) {
            int t = __shfl_up(incl, (unsigned)off, 64);
            if (lane >= off) incl += t;
        }
        if (lane == 63) wsum[wid] = incl;
        __syncthreads();
        int woff = 0;
        for (int w = 0; w < wid; ++w) woff += wsum[w];
        int carry = carry_s;
        int excl = carry + woff + incl - v;
        if (idx < n) { row_start[idx] = excl; cursor[idx] = excl; }
        __syncthreads();
        if (tid == 1023) carry_s = carry + woff + incl;
        __syncthreads();
    }
    if (tid == 0) row_start[n] = carry_s;
}

// ---------------------------------------------------------------------------
// Kernel 3: scatter edges into dst-sorted CSR
// ---------------------------------------------------------------------------
__global__ __launch_bounds__(256) void scatter_kernel(
    const int* __restrict__ src, const int* __restrict__ dst,
    int* __restrict__ cursor, int* __restrict__ csr_src, int ne)
{
    int i = blockIdx.x * blockDim.x + threadIdx.x;
    int stride = gridDim.x * blockDim.x;
    for (; i < ne; i += stride) {
        int pos = atomicAdd(&cursor[dst[i]], 1);
        csr_src[pos] = src[i];
    }
}

// ---------------------------------------------------------------------------
// Kernel 3b: Wt[col][k] = bf16(W[k][col])   (128 x 256 bf16, transposed)
// ---------------------------------------------------------------------------
__global__ __launch_bounds__(256) void wconv_kernel(
    const float* __restrict__ W, unsigned short* __restrict__ Wt)
{
    int t = blockIdx.x * 256 + threadIdx.x;
    if (t >= IN_DIM * OUT_DIM) return;
    int k = t >> 7, c = t & 127;
    Wt[c * IN_DIM + k] = f2bf(W[t]);
}

// ---------------------------------------------------------------------------
// Kernel 4: h = bf16( (emb[nodes]*rsqrt(max(deg,1))) @ W )   via bf16 MFMA.
// Block: 256 thr (4 waves), tile 64 rows x 128 cols, K=256 in 8 steps of 32.
// Wave w: rows (w&1)*32..+32, cols (w>>1)*64..+64.
// MFMA operand order: A-op = Wt frag (M=cols), B-op = feat frag (N=rows)
//   -> D reg index = consecutive h-cols, lane&15 = h-row (coalesced 8B stores).
// LDS row stride 40 ushorts (80 B): 16B-aligned, bank-rotating (conflict-free).
// ---------------------------------------------------------------------------
__global__ __launch_bounds__(256) void gemm1_mfma_kernel(
    const int* __restrict__ nodes, const float* __restrict__ emb,
    const unsigned short* __restrict__ Wt, const int* __restrict__ cnt_out,
    unsigned short* __restrict__ h, int n)
{
    __shared__ unsigned short A_lds[64 * 40];
    __shared__ unsigned short B_lds[128 * 40];
    __shared__ int   snode[64];
    __shared__ float sscale[64];

    const int tid = threadIdx.x;
    const int m0  = blockIdx.x * 64;

    if (tid < 64) {
        int gr = m0 + tid;
        snode[tid]  = (gr < n) ? nodes[gr] : 0;
        sscale[tid] = (gr < n) ? rsqrtf(fmaxf((float)cnt_out[gr], 1.0f)) : 0.0f;
    }
    __syncthreads();

    // staging roles: A: 4 thr/row x 8 floats; B: 2 thr/col x 16 bf16
    const int arow = tid >> 2, aq = tid & 3;
    const int bcol = tid >> 1, bh = tid & 1;
    const float* aptr = emb + (size_t)snode[arow] * IN_DIM + aq * 8;
    const float ascale = sscale[arow];
    const unsigned short* bptr = Wt + bcol * IN_DIM + bh * 16;

    float    ar[8];
    unsigned bw[8];

#define LOAD_REGS(KK) do {                                          \
        const floatx4 v0 = *(const floatx4*)(aptr + (KK) * 32);     \
        const floatx4 v1 = *(const floatx4*)(aptr + (KK) * 32 + 4); \
        ar[0]=v0[0]; ar[1]=v0[1]; ar[2]=v0[2]; ar[3]=v0[3];         \
        ar[4]=v1[0]; ar[5]=v1[1]; ar[6]=v1[2]; ar[7]=v1[3];         \
        const uint4 w0 = *(const uint4*)(bptr + (KK) * 32);         \
        const uint4 w1 = *(const uint4*)(bptr + (KK) * 32 + 8);     \
        bw[0]=w0.x; bw[1]=w0.y; bw[2]=w0.z; bw[3]=w0.w;             \
        bw[4]=w1.x; bw[5]=w1.y; bw[6]=w1.z; bw[7]=w1.w;             \
    } while (0)

#define WRITE_LDS() do {                                            \
        union { unsigned short s[8]; uint4 v; } ua;                 \
        _Pragma("unroll")                                           \
        for (int i = 0; i < 8; i++) ua.s[i] = f2bf(ar[i] * ascale); \
        *(uint4*)&A_lds[arow * 40 + aq * 8] = ua.v;                 \
        uint4 b0, b1;                                               \
        b0.x=bw[0]; b0.y=bw[1]; b0.z=bw[2]; b0.w=bw[3];             \
        b1.x=bw[4]; b1.y=bw[5]; b1.z=bw[6]; b1.w=bw[7];             \
        *(uint4*)&B_lds[bcol * 40 + bh * 16]     = b0;              \
        *(uint4*)&B_lds[bcol * 40 + bh * 16 + 8] = b1;              \
    } while (0)

    const int wave = tid >> 6, lane = tid & 63;
    const int rbase = (wave & 1) * 32 + (lane & 15);
    const int cbase = (wave >> 1) * 64 + (lane & 15);
    const int koff  = (lane >> 4) * 8;

    floatx4 acc[2][4];
#pragma unroll
    for (int i = 0; i < 2; i++)
#pragma unroll
        for (int j = 0; j < 4; j++) acc[i][j] = (floatx4){0.f, 0.f, 0.f, 0.f};

    LOAD_REGS(0);
    WRITE_LDS();

    for (int kk = 0; kk < 8; ++kk) {
        if (kk < 7) LOAD_REGS(kk + 1);
        __syncthreads();
        short8 af0 = *(const short8*)&A_lds[rbase * 40 + koff];
        short8 af1 = *(const short8*)&A_lds[(rbase + 16) * 40 + koff];
        short8 bf[4];
#pragma unroll
        for (int ct = 0; ct < 4; ct++)
            bf[ct] = *(const short8*)&B_lds[(cbase + ct * 16) * 40 + koff];
#pragma unroll
        for (int ct = 0; ct < 4; ct++) {
            acc[0][ct] = __builtin_amdgcn_mfma_f32_16x16x32_bf16(bf[ct], af0, acc[0][ct], 0, 0, 0);
            acc[1][ct] = __builtin_amdgcn_mfma_f32_16x16x32_bf16(bf[ct], af1, acc[1][ct], 0, 0, 0);
        }
        __syncthreads();
        if (kk < 7) WRITE_LDS();
    }

    // epilogue: lane&15 = row, (lane>>4)*4+reg = col (4 consecutive) -> 8B store
#pragma unroll
    for (int rt = 0; rt < 2; rt++) {
        int grow = m0 + (wave & 1) * 32 + rt * 16 + (lane & 15);
        if (grow < n) {
#pragma unroll
            for (int ct = 0; ct < 4; ct++) {
                int col = (wave >> 1) * 64 + ct * 16 + (lane >> 4) * 4;
                union { unsigned short s[4]; uint2 v; } o;
                o.s[0] = f2bf(acc[rt][ct][0]);
                o.s[1] = f2bf(acc[rt][ct][1]);
                o.s[2] = f2bf(acc[rt][ct][2]);
                o.s[3] = f2bf(acc[rt][ct][3]);
                *(uint2*)&h[(size_t)grow * OUT_DIM + col] = o.v;
            }
        }
    }
#undef LOAD_REGS
#undef WRITE_LDS
}

// ---------------------------------------------------------------------------
// Kernel 5: fused CSR-SpMM (bf16 h, 256B/edge) + norm + bias + MLP.
// One wave per dst row, 4-edge unroll; mlp_w transposed bf16 in LDS.
// ---------------------------------------------------------------------------
__global__ __launch_bounds__(256) void spmm_csr_kernel(
    const int* __restrict__ row_start, const int* __restrict__ row_end,
    const int* __restrict__ csr_src, const unsigned short* __restrict__ h,
    const float* __restrict__ bias, const float* __restrict__ mlp_w,
    const float* __restrict__ mlp_b,
    float* __restrict__ out_feat, float* __restrict__ out_logits, int n)
{
    __shared__ unsigned short s_mlpwT[N_CLS][136]; // [class][k], padded
    __shared__ float s_fo[4][OUT_DIM];
    __shared__ float s_mlpb[N_CLS];
    __shared__ float s_bias[OUT_DIM];

    const int tid = threadIdx.x;
    for (int i = tid; i < OUT_DIM * N_CLS; i += 256) {
        int k = i / N_CLS, j = i - k * N_CLS;
        s_mlpwT[j][k] = f2bf(mlp_w[i]);
    }
    if (tid < N_CLS)   s_mlpb[tid] = mlp_b[tid];
    if (tid < OUT_DIM) s_bias[tid] = bias[tid];
    __syncthreads();

    const int wid = tid >> 6, lane = tid & 63;
    const int c2 = lane * 2;

    for (int row = blockIdx.x * 4 + wid; row < n; row += gridDim.x * 4) {
        const int rs = row_start[row];
        const int re = row_end[row];

        float a0 = 0.f, a1 = 0.f, b0 = 0.f, b1 = 0.f;
        float d0 = 0.f, d1 = 0.f, e0 = 0.f, e1 = 0.f;
        int j = rs;
        for (; j + 3 < re; j += 4) {
            int s0 = csr_src[j], s1 = csr_src[j + 1];
            int s2 = csr_src[j + 2], s3 = csr_src[j + 3];
            unsigned v0 = *(const unsigned*)&h[(size_t)s0 * OUT_DIM + c2];
            unsigned v1 = *(const unsigned*)&h[(size_t)s1 * OUT_DIM + c2];
            unsigned v2 = *(const unsigned*)&h[(size_t)s2 * OUT_DIM + c2];
            unsigned v3 = *(const unsigned*)&h[(size_t)s3 * OUT_DIM + c2];
            union { unsigned u; float f; } t;
            t.u = v0 << 16;          a0 += t.f;
            t.u = v0 & 0xffff0000u;  a1 += t.f;
            t.u = v1 << 16;          b0 += t.f;
            t.u = v1 & 0xffff0000u;  b1 += t.f;
            t.u = v2 << 16;          d0 += t.f;
            t.u = v2 & 0xffff0000u;  d1 += t.f;
            t.u = v3 << 16;          e0 += t.f;
            t.u = v3 & 0xffff0000u;  e1 += t.f;
        }
        for (; j < re; ++j) {
            int s0 = csr_src[j];
            unsigned v0 = *(const unsigned*)&h[(size_t)s0 * OUT_DIM + c2];
            union { unsigned u; float f; } t;
            t.u = v0 << 16;          a0 += t.f;
            t.u = v0 & 0xffff0000u;  a1 += t.f;
        }

        const float nd = rsqrtf(fmaxf((float)(re - rs), 1.0f));
        const float f0 = ((a0 + b0) + (d0 + e0)) * nd + s_bias[c2];
        const float f1 = ((a1 + b1) + (d1 + e1)) * nd + s_bias[c2 + 1];
        *(float2*)&out_feat[(size_t)row * OUT_DIM + c2] = make_float2(f0, f1);

        s_fo[wid][c2]     = f0;
        s_fo[wid][c2 + 1] = f1;
        asm volatile("s_waitcnt lgkmcnt(0)" ::: "memory"); // wave-sync LDS

        if (lane < N_CLS) {
            float acc = s_mlpb[lane];
#pragma unroll
            for (int k0 = 0; k0 < OUT_DIM / 8; k0++) {
                short8 wv = *(const short8*)&s_mlpwT[lane][k0 * 8];
                floatx4 fa = *(const floatx4*)&s_fo[wid][k0 * 8];
                floatx4 fb = *(const floatx4*)&s_fo[wid][k0 * 8 + 4];
                union { unsigned u; float f; } t;
#pragma unroll
                for (int i = 0; i < 4; i++) {
                    t.u = ((unsigned)(unsigned short)wv[i]) << 16;
                    acc += fa[i] * t.f;
                }
#pragma unroll
                for (int i = 0; i < 4; i++) {
                    t.u = ((unsigned)(unsigned short)wv[4 + i]) << 16;
                    acc += fb[i] * t.f;
                }
            }
            out_logits[(size_t)row * N_CLS + lane] = acc;
        }
    }
}

// ---------------------------------------------------------------------------
extern "C" void kernel_launch(void* const* d_in, const int* in_sizes, int n_in,
                              void* d_out, int out_size, void* d_ws, size_t ws_size,
                              hipStream_t stream) {
    const int*   nodes = (const int*)d_in[0];
    const int*   src   = (const int*)d_in[1];
    const int*   dst   = (const int*)d_in[2];
    const float* emb   = (const float*)d_in[3];
    const float* W     = (const float*)d_in[4];
    const float* b     = (const float*)d_in[5];
    const float* mlp_w = (const float*)d_in[6];
    const float* mlp_b = (const float*)d_in[7];

    const int n  = in_sizes[0];   // 50000
    const int ne = in_sizes[1];   // 800000

    // ws layout: cnt_out[n] | cnt_in[n] | row_start[n+1] | cursor[n] |
    //            csr_src[ne] | Wt bf16[128*256] | h bf16[n*128]
    int* cnt_out   = (int*)d_ws;
    int* cnt_in    = cnt_out + n;
    int* row_start = cnt_in + n;          // n+1
    int* cursor    = row_start + n + 1;
    int* csr_src   = cursor + n;
    size_t off = ((size_t)(4 * n + 1) + (size_t)ne) * sizeof(int);
    off = (off + 15) & ~(size_t)15;
    unsigned short* Wt = (unsigned short*)((char*)d_ws + off);
    off += (size_t)IN_DIM * OUT_DIM * sizeof(unsigned short);
    off = (off + 15) & ~(size_t)15;
    unsigned short* h = (unsigned short*)((char*)d_ws + off);

    float* out_feat   = (float*)d_out;                    // n*128
    float* out_logits = out_feat + (size_t)n * OUT_DIM;   // n*40

    hipMemsetAsync(d_ws, 0, (size_t)2 * n * sizeof(int), stream);

    deg_kernel<<<1024, 256, 0, stream>>>(src, dst, cnt_out, cnt_in, ne);
    scan_kernel<<<1, 1024, 0, stream>>>(cnt_in, row_start, cursor, n);
    scatter_kernel<<<1024, 256, 0, stream>>>(src, dst, cursor, csr_src, ne);
    wconv_kernel<<<(IN_DIM * OUT_DIM + 255) / 256, 256, 0, stream>>>(W, Wt);
    gemm1_mfma_kernel<<<(n + 63) / 64, 256, 0, stream>>>(nodes, emb, Wt, cnt_out, h, n);
    spmm_csr_kernel<<<(n + 3) / 4, 256, 0, stream>>>(
        row_start, cursor, csr_src, h, b, mlp_w, mlp_b,
        out_feat, out_logits, n);
}

// Round 4
// 214.699 us; speedup vs baseline: 7.2894x; 1.2787x over previous
//
#include <hip/hip_runtime.h>

#define IN_DIM 256
#define OUT_DIM 128
#define N_CLS 40

typedef __attribute__((ext_vector_type(8))) short short8;
typedef __attribute__((ext_vector_type(4))) float floatx4;

static __device__ __forceinline__ unsigned short f2bf(float f) {
    union { float f; unsigned u; } v; v.f = f;
    unsigned r = v.u + 0x7FFF + ((v.u >> 16) & 1);
    return (unsigned short)(r >> 16);
}

// ---------------------------------------------------------------------------
// Kernel 1: int histograms (int4-vectorized edge loads)
// ---------------------------------------------------------------------------
__global__ __launch_bounds__(256) void deg_kernel(
    const int* __restrict__ src, const int* __restrict__ dst,
    int* __restrict__ cnt_out, int* __restrict__ cnt_in, int ne)
{
    int i = blockIdx.x * blockDim.x + threadIdx.x;
    int stride = gridDim.x * blockDim.x;
    int nv = ne >> 2;
    for (int k = i; k < nv; k += stride) {
        int4 s = ((const int4*)src)[k];
        int4 d = ((const int4*)dst)[k];
        atomicAdd(&cnt_out[s.x], 1); atomicAdd(&cnt_out[s.y], 1);
        atomicAdd(&cnt_out[s.z], 1); atomicAdd(&cnt_out[s.w], 1);
        atomicAdd(&cnt_in[d.x], 1);  atomicAdd(&cnt_in[d.y], 1);
        atomicAdd(&cnt_in[d.z], 1);  atomicAdd(&cnt_in[d.w], 1);
    }
    int t = (nv << 2) + i;
    if (t < ne) {
        atomicAdd(&cnt_out[src[t]], 1);
        atomicAdd(&cnt_in[dst[t]], 1);
    }
}

// ---------------------------------------------------------------------------
// Kernel 2: single-block exclusive scan, 8 elems/thread (7 chunks for n=50k)
// ---------------------------------------------------------------------------
__global__ __launch_bounds__(1024) void scan_kernel(
    const int* __restrict__ cnt, int* __restrict__ row_start,
    int* __restrict__ cursor, int n)
{
    __shared__ int wsum[16];
    __shared__ int carry_s;
    const int tid = threadIdx.x;
    const int lane = tid & 63, wid = tid >> 6;
    if (tid == 0) carry_s = 0;
    __syncthreads();

    for (int chunk = 0; chunk < n; chunk += 8192) {
        int base = chunk + tid * 8;
        int v[8];
        if (base + 8 <= n) {
            int4 a = *(const int4*)&cnt[base];
            int4 b = *(const int4*)&cnt[base + 4];
            v[0]=a.x; v[1]=a.y; v[2]=a.z; v[3]=a.w;
            v[4]=b.x; v[5]=b.y; v[6]=b.z; v[7]=b.w;
        } else {
#pragma unroll
            for (int t = 0; t < 8; t++) v[t] = (base + t < n) ? cnt[base + t] : 0;
        }
        int tsum = 0;
#pragma unroll
        for (int t = 0; t < 8; t++) tsum += v[t];

        int incl = tsum;
#pragma unroll
        for (int off = 1; off < 64; off <<= 1) {
            int q = __shfl_up(incl, (unsigned)off, 64);
            if (lane >= off) incl += q;
        }
        if (lane == 63) wsum[wid] = incl;
        __syncthreads();
        int woff = 0;
        for (int w = 0; w < wid; ++w) woff += wsum[w];
        int carry = carry_s;
        int run = carry + woff + (incl - tsum);
        if (base + 8 <= n) {
            int o[8];
#pragma unroll
            for (int t = 0; t < 8; t++) { o[t] = run; run += v[t]; }
            int4 r0, r1;
            r0.x=o[0]; r0.y=o[1]; r0.z=o[2]; r0.w=o[3];
            r1.x=o[4]; r1.y=o[5]; r1.z=o[6]; r1.w=o[7];
            *(int4*)&row_start[base]     = r0;
            *(int4*)&row_start[base + 4] = r1;
            *(int4*)&cursor[base]        = r0;
            *(int4*)&cursor[base + 4]    = r1;
        } else {
#pragma unroll
            for (int t = 0; t < 8; t++) {
                if (base + t < n) { row_start[base + t] = run; cursor[base + t] = run; }
                run += v[t];
            }
        }
        __syncthreads();
        if (tid == 1023) carry_s = carry + woff + incl;
        __syncthreads();
    }
    if (tid == 0) row_start[n] = carry_s;
}

// ---------------------------------------------------------------------------
// Kernel 3: scatter edges into dst-sorted CSR (int4-vectorized)
// ---------------------------------------------------------------------------
__global__ __launch_bounds__(256) void scatter_kernel(
    const int* __restrict__ src, const int* __restrict__ dst,
    int* __restrict__ cursor, int* __restrict__ csr_src, int ne)
{
    int i = blockIdx.x * blockDim.x + threadIdx.x;
    int stride = gridDim.x * blockDim.x;
    int nv = ne >> 2;
    for (int k = i; k < nv; k += stride) {
        int4 s = ((const int4*)src)[k];
        int4 d = ((const int4*)dst)[k];
        csr_src[atomicAdd(&cursor[d.x], 1)] = s.x;
        csr_src[atomicAdd(&cursor[d.y], 1)] = s.y;
        csr_src[atomicAdd(&cursor[d.z], 1)] = s.z;
        csr_src[atomicAdd(&cursor[d.w], 1)] = s.w;
    }
    int t = (nv << 2) + i;
    if (t < ne) csr_src[atomicAdd(&cursor[dst[t]], 1)] = src[t];
}

// ---------------------------------------------------------------------------
// Kernel 3b: Wt[col][k] = bf16(W[k][col])
// ---------------------------------------------------------------------------
__global__ __launch_bounds__(256) void wconv_kernel(
    const float* __restrict__ W, unsigned short* __restrict__ Wt)
{
    int t = blockIdx.x * 256 + threadIdx.x;
    if (t >= IN_DIM * OUT_DIM) return;
    int k = t >> 7, c = t & 127;
    Wt[c * IN_DIM + k] = f2bf(W[t]);
}

// ---------------------------------------------------------------------------
// Kernel 4: h = bf16( (emb[nodes]*rsqrt(max(deg,1))) @ W )  via bf16 MFMA.
// (unchanged from round 3)
// ---------------------------------------------------------------------------
__global__ __launch_bounds__(256) void gemm1_mfma_kernel(
    const int* __restrict__ nodes, const float* __restrict__ emb,
    const unsigned short* __restrict__ Wt, const int* __restrict__ cnt_out,
    unsigned short* __restrict__ h, int n)
{
    __shared__ unsigned short A_lds[64 * 40];
    __shared__ unsigned short B_lds[128 * 40];
    __shared__ int   snode[64];
    __shared__ float sscale[64];

    const int tid = threadIdx.x;
    const int m0  = blockIdx.x * 64;

    if (tid < 64) {
        int gr = m0 + tid;
        snode[tid]  = (gr < n) ? nodes[gr] : 0;
        sscale[tid] = (gr < n) ? rsqrtf(fmaxf((float)cnt_out[gr], 1.0f)) : 0.0f;
    }
    __syncthreads();

    const int arow = tid >> 2, aq = tid & 3;
    const int bcol = tid >> 1, bh = tid & 1;
    const float* aptr = emb + (size_t)snode[arow] * IN_DIM + aq * 8;
    const float ascale = sscale[arow];
    const unsigned short* bptr = Wt + bcol * IN_DIM + bh * 16;

    float    ar[8];
    unsigned bw[8];

#define LOAD_REGS(KK) do {                                          \
        const floatx4 v0 = *(const floatx4*)(aptr + (KK) * 32);     \
        const floatx4 v1 = *(const floatx4*)(aptr + (KK) * 32 + 4); \
        ar[0]=v0[0]; ar[1]=v0[1]; ar[2]=v0[2]; ar[3]=v0[3];         \
        ar[4]=v1[0]; ar[5]=v1[1]; ar[6]=v1[2]; ar[7]=v1[3];         \
        const uint4 w0 = *(const uint4*)(bptr + (KK) * 32);         \
        const uint4 w1 = *(const uint4*)(bptr + (KK) * 32 + 8);     \
        bw[0]=w0.x; bw[1]=w0.y; bw[2]=w0.z; bw[3]=w0.w;             \
        bw[4]=w1.x; bw[5]=w1.y; bw[6]=w1.z; bw[7]=w1.w;             \
    } while (0)

#define WRITE_LDS() do {                                            \
        union { unsigned short s[8]; uint4 v; } ua;                 \
        _Pragma("unroll")                                           \
        for (int i = 0; i < 8; i++) ua.s[i] = f2bf(ar[i] * ascale); \
        *(uint4*)&A_lds[arow * 40 + aq * 8] = ua.v;                 \
        uint4 b0, b1;                                               \
        b0.x=bw[0]; b0.y=bw[1]; b0.z=bw[2]; b0.w=bw[3];             \
        b1.x=bw[4]; b1.y=bw[5]; b1.z=bw[6]; b1.w=bw[7];             \
        *(uint4*)&B_lds[bcol * 40 + bh * 16]     = b0;              \
        *(uint4*)&B_lds[bcol * 40 + bh * 16 + 8] = b1;              \
    } while (0)

    const int wave = tid >> 6, lane = tid & 63;
    const int rbase = (wave & 1) * 32 + (lane & 15);
    const int cbase = (wave >> 1) * 64 + (lane & 15);
    const int koff  = (lane >> 4) * 8;

    floatx4 acc[2][4];
#pragma unroll
    for (int i = 0; i < 2; i++)
#pragma unroll
        for (int j = 0; j < 4; j++) acc[i][j] = (floatx4){0.f, 0.f, 0.f, 0.f};

    LOAD_REGS(0);
    WRITE_LDS();

    for (int kk = 0; kk < 8; ++kk) {
        if (kk < 7) LOAD_REGS(kk + 1);
        __syncthreads();
        short8 af0 = *(const short8*)&A_lds[rbase * 40 + koff];
        short8 af1 = *(const short8*)&A_lds[(rbase + 16) * 40 + koff];
        short8 bf[4];
#pragma unroll
        for (int ct = 0; ct < 4; ct++)
            bf[ct] = *(const short8*)&B_lds[(cbase + ct * 16) * 40 + koff];
#pragma unroll
        for (int ct = 0; ct < 4; ct++) {
            acc[0][ct] = __builtin_amdgcn_mfma_f32_16x16x32_bf16(bf[ct], af0, acc[0][ct], 0, 0, 0);
            acc[1][ct] = __builtin_amdgcn_mfma_f32_16x16x32_bf16(bf[ct], af1, acc[1][ct], 0, 0, 0);
        }
        __syncthreads();
        if (kk < 7) WRITE_LDS();
    }

#pragma unroll
    for (int rt = 0; rt < 2; rt++) {
        int grow = m0 + (wave & 1) * 32 + rt * 16 + (lane & 15);
        if (grow < n) {
#pragma unroll
            for (int ct = 0; ct < 4; ct++) {
                int col = (wave >> 1) * 64 + ct * 16 + (lane >> 4) * 4;
                union { unsigned short s[4]; uint2 v; } o;
                o.s[0] = f2bf(acc[rt][ct][0]);
                o.s[1] = f2bf(acc[rt][ct][1]);
                o.s[2] = f2bf(acc[rt][ct][2]);
                o.s[3] = f2bf(acc[rt][ct][3]);
                *(uint2*)&h[(size_t)grow * OUT_DIM + col] = o.v;
            }
        }
    }
#undef LOAD_REGS
#undef WRITE_LDS
}

// ---------------------------------------------------------------------------
// Kernel 5: CSR-SpMM + norm + bias only (no LDS, no MLP). One wave per row,
// 8-edge unroll, bias held in registers.
// ---------------------------------------------------------------------------
__global__ __launch_bounds__(256) void spmm_csr_kernel(
    const int* __restrict__ row_start, const int* __restrict__ row_end,
    const int* __restrict__ csr_src, const unsigned short* __restrict__ h,
    const float* __restrict__ bias, float* __restrict__ out_feat, int n)
{
    const int lane = threadIdx.x & 63;
    const int c2 = lane * 2;
    const float bi0 = bias[c2], bi1 = bias[c2 + 1];
    const int wave0 = blockIdx.x * 4 + (threadIdx.x >> 6);
    const int nwaves = gridDim.x * 4;

    for (int row = wave0; row < n; row += nwaves) {
        const int rs = row_start[row];
        const int re = row_end[row];

        float aL[4] = {0.f, 0.f, 0.f, 0.f};
        float aH[4] = {0.f, 0.f, 0.f, 0.f};
        int j = rs;
        for (; j + 7 < re; j += 8) {
            int s[8];
#pragma unroll
            for (int t = 0; t < 8; t++) s[t] = csr_src[j + t];
            unsigned v[8];
#pragma unroll
            for (int t = 0; t < 8; t++)
                v[t] = *(const unsigned*)&h[(size_t)s[t] * OUT_DIM + c2];
#pragma unroll
            for (int t = 0; t < 8; t++) {
                union { unsigned u; float f; } x, y;
                x.u = v[t] << 16;
                y.u = v[t] & 0xffff0000u;
                aL[t & 3] += x.f;
                aH[t & 3] += y.f;
            }
        }
        for (; j < re; ++j) {
            int s0 = csr_src[j];
            unsigned v0 = *(const unsigned*)&h[(size_t)s0 * OUT_DIM + c2];
            union { unsigned u; float f; } x, y;
            x.u = v0 << 16;
            y.u = v0 & 0xffff0000u;
            aL[0] += x.f;
            aH[0] += y.f;
        }

        const float nd = rsqrtf(fmaxf((float)(re - rs), 1.0f));
        const float f0 = ((aL[0] + aL[1]) + (aL[2] + aL[3])) * nd + bi0;
        const float f1 = ((aH[0] + aH[1]) + (aH[2] + aH[3])) * nd + bi1;
        *(float2*)&out_feat[(size_t)row * OUT_DIM + c2] = make_float2(f0, f1);
    }
}

// ---------------------------------------------------------------------------
// Kernel 6: logits = F @ mlp_w + mlp_b via MFMA.
// Block: 256 thr (4 waves); wave = 16 rows x 48 cls (3 tiles); K=128.
// B-frag loaded straight from global F (f32 -> bf16 in regs); A = mlp_wT LDS.
// ---------------------------------------------------------------------------
__global__ __launch_bounds__(256) void mlp_mfma_kernel(
    const float* __restrict__ F, const float* __restrict__ mlp_w,
    const float* __restrict__ mlp_b, float* __restrict__ out_logits, int n)
{
    __shared__ unsigned short A_lds[48 * 136];
    __shared__ float s_mlpb[48];

    const int tid = threadIdx.x;
    for (int i = tid; i < 48 * 128; i += 256) {
        int cls = i >> 7, k = i & 127;
        A_lds[cls * 136 + k] =
            (cls < N_CLS) ? f2bf(mlp_w[(size_t)k * N_CLS + cls]) : (unsigned short)0;
    }
    if (tid < 48) s_mlpb[tid] = (tid < N_CLS) ? mlp_b[tid] : 0.f;
    __syncthreads();

    const int wave = tid >> 6, lane = tid & 63;
    const int r = lane & 15, koff = (lane >> 4) * 8;
    const int row = blockIdx.x * 64 + wave * 16 + r;
    const int rowc = (row < n) ? row : (n - 1);
    const float* fp = F + (size_t)rowc * OUT_DIM + koff;

    floatx4 acc[3];
#pragma unroll
    for (int ct = 0; ct < 3; ct++) acc[ct] = (floatx4){0.f, 0.f, 0.f, 0.f};

#pragma unroll
    for (int kk = 0; kk < 4; kk++) {
        floatx4 v0 = *(const floatx4*)(fp + kk * 32);
        floatx4 v1 = *(const floatx4*)(fp + kk * 32 + 4);
        union { unsigned short s[8]; short8 v; } bfr;
#pragma unroll
        for (int i = 0; i < 4; i++) {
            bfr.s[i]     = f2bf(v0[i]);
            bfr.s[4 + i] = f2bf(v1[i]);
        }
#pragma unroll
        for (int ct = 0; ct < 3; ct++) {
            short8 af = *(const short8*)&A_lds[(ct * 16 + r) * 136 + kk * 32 + koff];
            acc[ct] = __builtin_amdgcn_mfma_f32_16x16x32_bf16(af, bfr.v, acc[ct], 0, 0, 0);
        }
    }

    if (row < n) {
#pragma unroll
        for (int ct = 0; ct < 3; ct++)
#pragma unroll
            for (int i = 0; i < 4; i++) {
                int cls = ct * 16 + (lane >> 4) * 4 + i;
                if (cls < N_CLS)
                    out_logits[(size_t)row * N_CLS + cls] = acc[ct][i] + s_mlpb[cls];
            }
    }
}

// ---------------------------------------------------------------------------
extern "C" void kernel_launch(void* const* d_in, const int* in_sizes, int n_in,
                              void* d_out, int out_size, void* d_ws, size_t ws_size,
                              hipStream_t stream) {
    const int*   nodes = (const int*)d_in[0];
    const int*   src   = (const int*)d_in[1];
    const int*   dst   = (const int*)d_in[2];
    const float* emb   = (const float*)d_in[3];
    const float* W     = (const float*)d_in[4];
    const float* b     = (const float*)d_in[5];
    const float* mlp_w = (const float*)d_in[6];
    const float* mlp_b = (const float*)d_in[7];

    const int n  = in_sizes[0];   // 50000
    const int ne = in_sizes[1];   // 800000

    // ws layout (ints): cnt_out[n] | cnt_in[n] | row_start[n+8] | cursor[n] |
    //                   csr_src[ne] | then bf16 Wt[128*256] | bf16 h[n*128]
    int* cnt_out   = (int*)d_ws;
    int* cnt_in    = cnt_out + n;
    int* row_start = cnt_in + n;            // n+1 used, padded to n+8
    int* cursor    = row_start + n + 8;     // 16B-aligned
    int* csr_src   = cursor + n;
    size_t off = ((size_t)(4 * n + 8) + (size_t)ne) * sizeof(int);
    off = (off + 15) & ~(size_t)15;
    unsigned short* Wt = (unsigned short*)((char*)d_ws + off);
    off += (size_t)IN_DIM * OUT_DIM * sizeof(unsigned short);
    off = (off + 15) & ~(size_t)15;
    unsigned short* h = (unsigned short*)((char*)d_ws + off);

    float* out_feat   = (float*)d_out;                    // n*128
    float* out_logits = out_feat + (size_t)n * OUT_DIM;   // n*40

    hipMemsetAsync(d_ws, 0, (size_t)2 * n * sizeof(int), stream);

    deg_kernel<<<1024, 256, 0, stream>>>(src, dst, cnt_out, cnt_in, ne);
    scan_kernel<<<1, 1024, 0, stream>>>(cnt_in, row_start, cursor, n);
    scatter_kernel<<<1024, 256, 0, stream>>>(src, dst, cursor, csr_src, ne);
    wconv_kernel<<<(IN_DIM * OUT_DIM + 255) / 256, 256, 0, stream>>>(W, Wt);
    gemm1_mfma_kernel<<<(n + 63) / 64, 256, 0, stream>>>(nodes, emb, Wt, cnt_out, h, n);
    spmm_csr_kernel<<<(n + 3) / 4, 256, 0, stream>>>(
        row_start, cursor, csr_src, h, b, out_feat, n);
    mlp_mfma_kernel<<<(n + 63) / 64, 256, 0, stream>>>(
        out_feat, mlp_w, mlp_b, out_logits, n);
}

// Round 5
// 157.431 us; speedup vs baseline: 9.9410x; 1.3638x over previous
//
#include <hip/hip_runtime.h>

#define IN_DIM 256
#define OUT_DIM 128
#define N_CLS 40

#define SLICE 8192     // nodes per LDS histogram slice (2 x 32 KB LDS)
#define NE_CH 20       // edge chunks

typedef __attribute__((ext_vector_type(8))) short short8;
typedef __attribute__((ext_vector_type(4))) float floatx4;

static __device__ __forceinline__ unsigned short f2bf(float f) {
    union { float f; unsigned u; } v; v.f = f;
    unsigned r = v.u + 0x7FFF + ((v.u >> 16) & 1);
    return (unsigned short)(r >> 16);
}

// ---------------------------------------------------------------------------
// Kernel 1: LDS-privatized histograms -> partial_out/partial_in [NE_CH][n].
// Block (s,e): node slice s, edge chunk e. No global atomics.
// ---------------------------------------------------------------------------
__global__ __launch_bounds__(256) void hist_kernel(
    const int* __restrict__ src, const int* __restrict__ dst,
    int* __restrict__ partial_out, int* __restrict__ partial_in,
    int ne, int n, int chunk)
{
    __shared__ __align__(16) int lh_out[SLICE];
    __shared__ __align__(16) int lh_in[SLICE];

    const int tid = threadIdx.x;
    const int s = blockIdx.x / NE_CH;
    const int e = blockIdx.x % NE_CH;
    const int lo = s * SLICE;
    const int hi = min(lo + SLICE, n);

    for (int i = tid; i < SLICE; i += 256) { lh_out[i] = 0; lh_in[i] = 0; }
    __syncthreads();

    const int start = e * chunk;
    const int end = min(start + chunk, ne);
    const int cnt4 = (end - start) >> 2;
    const int4* s4 = (const int4*)(src + start);
    const int4* d4 = (const int4*)(dst + start);
    for (int k = tid; k < cnt4; k += 256) {
        int4 sv = s4[k];
        int4 dv = d4[k];
        unsigned q;
        q = (unsigned)(sv.x - lo); if (q < SLICE) atomicAdd(&lh_out[q], 1);
        q = (unsigned)(sv.y - lo); if (q < SLICE) atomicAdd(&lh_out[q], 1);
        q = (unsigned)(sv.z - lo); if (q < SLICE) atomicAdd(&lh_out[q], 1);
        q = (unsigned)(sv.w - lo); if (q < SLICE) atomicAdd(&lh_out[q], 1);
        q = (unsigned)(dv.x - lo); if (q < SLICE) atomicAdd(&lh_in[q], 1);
        q = (unsigned)(dv.y - lo); if (q < SLICE) atomicAdd(&lh_in[q], 1);
        q = (unsigned)(dv.z - lo); if (q < SLICE) atomicAdd(&lh_in[q], 1);
        q = (unsigned)(dv.w - lo); if (q < SLICE) atomicAdd(&lh_in[q], 1);
    }
    for (int t = start + (cnt4 << 2) + tid; t < end; t += 256) {
        unsigned q;
        q = (unsigned)(src[t] - lo); if (q < SLICE) atomicAdd(&lh_out[q], 1);
        q = (unsigned)(dst[t] - lo); if (q < SLICE) atomicAdd(&lh_in[q], 1);
    }
    __syncthreads();

    // flush slice (non-atomic, int4)
    const int cnt = hi - lo;
    const int c4 = cnt >> 2;
    int4* po = (int4*)(partial_out + (size_t)e * n + lo);
    int4* pi = (int4*)(partial_in + (size_t)e * n + lo);
    for (int i = tid; i < c4; i += 256) {
        po[i] = ((const int4*)lh_out)[i];
        pi[i] = ((const int4*)lh_in)[i];
    }
    for (int i = (c4 << 2) + tid; i < cnt; i += 256) {
        partial_out[(size_t)e * n + lo + i] = lh_out[i];
        partial_in[(size_t)e * n + lo + i] = lh_in[i];
    }
}

// ---------------------------------------------------------------------------
// Kernel 2: reduce partials -> cnt_out, cnt_in; convert partial_in in-place
// to an EXCLUSIVE prefix along the chunk axis (for atomic-free scatter).
// ---------------------------------------------------------------------------
__global__ __launch_bounds__(256) void reduce_kernel(
    int* __restrict__ partial_out, int* __restrict__ partial_in,
    int* __restrict__ cnt_out, int* __restrict__ cnt_in, int n)
{
    const int g = blockIdx.x * 256 + threadIdx.x;   // group of 4 nodes
    const int ng4 = n >> 2;
    if (g < ng4) {
        const size_t base = (size_t)g * 4;
        int4 sum = make_int4(0, 0, 0, 0);
#pragma unroll
        for (int e = 0; e < NE_CH; e++) {
            int4 v = *(const int4*)(partial_out + (size_t)e * n + base);
            sum.x += v.x; sum.y += v.y; sum.z += v.z; sum.w += v.w;
        }
        *(int4*)(cnt_out + base) = sum;

        int4 run = make_int4(0, 0, 0, 0);
#pragma unroll
        for (int e = 0; e < NE_CH; e++) {
            int* p = partial_in + (size_t)e * n + base;
            int4 v = *(const int4*)p;
            *(int4*)p = run;
            run.x += v.x; run.y += v.y; run.z += v.z; run.w += v.w;
        }
        *(int4*)(cnt_in + base) = run;
    }
    // scalar tail for n not divisible by 4
    const int t = (ng4 << 2) + g;
    if (t < n) {
        int sum = 0;
#pragma unroll
        for (int e = 0; e < NE_CH; e++) sum += partial_out[(size_t)e * n + t];
        cnt_out[t] = sum;
        int run = 0;
#pragma unroll
        for (int e = 0; e < NE_CH; e++) {
            int v = partial_in[(size_t)e * n + t];
            partial_in[(size_t)e * n + t] = run;
            run += v;
        }
        cnt_in[t] = run;
    }
}

// ---------------------------------------------------------------------------
// Kernel 3: single-block exclusive scan of cnt_in -> row_start[n+1]
// ---------------------------------------------------------------------------
__global__ __launch_bounds__(1024) void scan_kernel(
    const int* __restrict__ cnt, int* __restrict__ row_start, int n)
{
    __shared__ int wsum[16];
    __shared__ int carry_s;
    const int tid = threadIdx.x;
    const int lane = tid & 63, wid = tid >> 6;
    if (tid == 0) carry_s = 0;
    __syncthreads();

    for (int chunk = 0; chunk < n; chunk += 8192) {
        int base = chunk + tid * 8;
        int v[8];
        if (base + 8 <= n) {
            int4 a = *(const int4*)&cnt[base];
            int4 b = *(const int4*)&cnt[base + 4];
            v[0]=a.x; v[1]=a.y; v[2]=a.z; v[3]=a.w;
            v[4]=b.x; v[5]=b.y; v[6]=b.z; v[7]=b.w;
        } else {
#pragma unroll
            for (int t = 0; t < 8; t++) v[t] = (base + t < n) ? cnt[base + t] : 0;
        }
        int tsum = 0;
#pragma unroll
        for (int t = 0; t < 8; t++) tsum += v[t];

        int incl = tsum;
#pragma unroll
        for (int off = 1; off < 64; off <<= 1) {
            int q = __shfl_up(incl, (unsigned)off, 64);
            if (lane >= off) incl += q;
        }
        if (lane == 63) wsum[wid] = incl;
        __syncthreads();
        int woff = 0;
        for (int w = 0; w < wid; ++w) woff += wsum[w];
        int carry = carry_s;
        int run = carry + woff + (incl - tsum);
        if (base + 8 <= n) {
            int o[8];
#pragma unroll
            for (int t = 0; t < 8; t++) { o[t] = run; run += v[t]; }
            int4 r0, r1;
            r0.x=o[0]; r0.y=o[1]; r0.z=o[2]; r0.w=o[3];
            r1.x=o[4]; r1.y=o[5]; r1.z=o[6]; r1.w=o[7];
            *(int4*)&row_start[base]     = r0;
            *(int4*)&row_start[base + 4] = r1;
        } else {
#pragma unroll
            for (int t = 0; t < 8; t++) {
                if (base + t < n) row_start[base + t] = run;
                run += v[t];
            }
        }
        __syncthreads();
        if (tid == 1023) carry_s = carry + woff + incl;
        __syncthreads();
    }
    if (tid == 0) row_start[n] = carry_s;
}

// ---------------------------------------------------------------------------
// Kernel 4: scatter with LDS cursors (no global atomics).
// Block (s,e): cursor[v] = row_start[v] + prefix_in[e][v]; LDS-atomic bump.
// Positions are disjoint across chunks by construction.
// ---------------------------------------------------------------------------
__global__ __launch_bounds__(256) void scatter_lds_kernel(
    const int* __restrict__ src, const int* __restrict__ dst,
    const int* __restrict__ row_start, const int* __restrict__ prefix_in,
    int* __restrict__ csr_src, int ne, int n, int chunk)
{
    __shared__ __align__(16) int cur[SLICE];

    const int tid = threadIdx.x;
    const int s = blockIdx.x / NE_CH;
    const int e = blockIdx.x % NE_CH;
    const int lo = s * SLICE;
    const int hi = min(lo + SLICE, n);
    const int cnt = hi - lo;

    const int c4 = cnt >> 2;
    for (int i = tid; i < c4; i += 256) {
        int4 rs = *(const int4*)(row_start + lo + i * 4);
        int4 pf = *(const int4*)(prefix_in + (size_t)e * n + lo + i * 4);
        rs.x += pf.x; rs.y += pf.y; rs.z += pf.z; rs.w += pf.w;
        ((int4*)cur)[i] = rs;
    }
    for (int i = (c4 << 2) + tid; i < cnt; i += 256)
        cur[i] = row_start[lo + i] + prefix_in[(size_t)e * n + lo + i];
    __syncthreads();

    const int start = e * chunk;
    const int end = min(start + chunk, ne);
    const int cnt4e = (end - start) >> 2;
    const int4* s4 = (const int4*)(src + start);
    const int4* d4 = (const int4*)(dst + start);
    for (int k = tid; k < cnt4e; k += 256) {
        int4 sv = s4[k];
        int4 dv = d4[k];
        unsigned q;
        q = (unsigned)(dv.x - lo); if (q < SLICE) csr_src[atomicAdd(&cur[q], 1)] = sv.x;
        q = (unsigned)(dv.y - lo); if (q < SLICE) csr_src[atomicAdd(&cur[q], 1)] = sv.y;
        q = (unsigned)(dv.z - lo); if (q < SLICE) csr_src[atomicAdd(&cur[q], 1)] = sv.z;
        q = (unsigned)(dv.w - lo); if (q < SLICE) csr_src[atomicAdd(&cur[q], 1)] = sv.w;
    }
    for (int t = start + (cnt4e << 2) + tid; t < end; t += 256) {
        unsigned q = (unsigned)(dst[t] - lo);
        if (q < SLICE) csr_src[atomicAdd(&cur[q], 1)] = src[t];
    }
}

// ---------------------------------------------------------------------------
// Kernel 5: Wt[col][k] = bf16(W[k][col])
// ---------------------------------------------------------------------------
__global__ __launch_bounds__(256) void wconv_kernel(
    const float* __restrict__ W, unsigned short* __restrict__ Wt)
{
    int t = blockIdx.x * 256 + threadIdx.x;
    if (t >= IN_DIM * OUT_DIM) return;
    int k = t >> 7, c = t & 127;
    Wt[c * IN_DIM + k] = f2bf(W[t]);
}

// ---------------------------------------------------------------------------
// Kernel 6: h = bf16( (emb[nodes]*rsqrt(max(deg,1))) @ W )  via bf16 MFMA.
// ---------------------------------------------------------------------------
__global__ __launch_bounds__(256) void gemm1_mfma_kernel(
    const int* __restrict__ nodes, const float* __restrict__ emb,
    const unsigned short* __restrict__ Wt, const int* __restrict__ cnt_out,
    unsigned short* __restrict__ h, int n)
{
    __shared__ unsigned short A_lds[64 * 40];
    __shared__ unsigned short B_lds[128 * 40];
    __shared__ int   snode[64];
    __shared__ float sscale[64];

    const int tid = threadIdx.x;
    const int m0  = blockIdx.x * 64;

    if (tid < 64) {
        int gr = m0 + tid;
        snode[tid]  = (gr < n) ? nodes[gr] : 0;
        sscale[tid] = (gr < n) ? rsqrtf(fmaxf((float)cnt_out[gr], 1.0f)) : 0.0f;
    }
    __syncthreads();

    const int arow = tid >> 2, aq = tid & 3;
    const int bcol = tid >> 1, bh = tid & 1;
    const float* aptr = emb + (size_t)snode[arow] * IN_DIM + aq * 8;
    const float ascale = sscale[arow];
    const unsigned short* bptr = Wt + bcol * IN_DIM + bh * 16;

    float    ar[8];
    unsigned bw[8];

#define LOAD_REGS(KK) do {                                          \
        const floatx4 v0 = *(const floatx4*)(aptr + (KK) * 32);     \
        const floatx4 v1 = *(const floatx4*)(aptr + (KK) * 32 + 4); \
        ar[0]=v0[0]; ar[1]=v0[1]; ar[2]=v0[2]; ar[3]=v0[3];         \
        ar[4]=v1[0]; ar[5]=v1[1]; ar[6]=v1[2]; ar[7]=v1[3];         \
        const uint4 w0 = *(const uint4*)(bptr + (KK) * 32);         \
        const uint4 w1 = *(const uint4*)(bptr + (KK) * 32 + 8);     \
        bw[0]=w0.x; bw[1]=w0.y; bw[2]=w0.z; bw[3]=w0.w;             \
        bw[4]=w1.x; bw[5]=w1.y; bw[6]=w1.z; bw[7]=w1.w;             \
    } while (0)

#define WRITE_LDS() do {                                            \
        union { unsigned short s[8]; uint4 v; } ua;                 \
        _Pragma("unroll")                                           \
        for (int i = 0; i < 8; i++) ua.s[i] = f2bf(ar[i] * ascale); \
        *(uint4*)&A_lds[arow * 40 + aq * 8] = ua.v;                 \
        uint4 b0, b1;                                               \
        b0.x=bw[0]; b0.y=bw[1]; b0.z=bw[2]; b0.w=bw[3];             \
        b1.x=bw[4]; b1.y=bw[5]; b1.z=bw[6]; b1.w=bw[7];             \
        *(uint4*)&B_lds[bcol * 40 + bh * 16]     = b0;              \
        *(uint4*)&B_lds[bcol * 40 + bh * 16 + 8] = b1;              \
    } while (0)

    const int wave = tid >> 6, lane = tid & 63;
    const int rbase = (wave & 1) * 32 + (lane & 15);
    const int cbase = (wave >> 1) * 64 + (lane & 15);
    const int koff  = (lane >> 4) * 8;

    floatx4 acc[2][4];
#pragma unroll
    for (int i = 0; i < 2; i++)
#pragma unroll
        for (int j = 0; j < 4; j++) acc[i][j] = (floatx4){0.f, 0.f, 0.f, 0.f};

    LOAD_REGS(0);
    WRITE_LDS();

    for (int kk = 0; kk < 8; ++kk) {
        if (kk < 7) LOAD_REGS(kk + 1);
        __syncthreads();
        short8 af0 = *(const short8*)&A_lds[rbase * 40 + koff];
        short8 af1 = *(const short8*)&A_lds[(rbase + 16) * 40 + koff];
        short8 bf[4];
#pragma unroll
        for (int ct = 0; ct < 4; ct++)
            bf[ct] = *(const short8*)&B_lds[(cbase + ct * 16) * 40 + koff];
#pragma unroll
        for (int ct = 0; ct < 4; ct++) {
            acc[0][ct] = __builtin_amdgcn_mfma_f32_16x16x32_bf16(bf[ct], af0, acc[0][ct], 0, 0, 0);
            acc[1][ct] = __builtin_amdgcn_mfma_f32_16x16x32_bf16(bf[ct], af1, acc[1][ct], 0, 0, 0);
        }
        __syncthreads();
        if (kk < 7) WRITE_LDS();
    }

#pragma unroll
    for (int rt = 0; rt < 2; rt++) {
        int grow = m0 + (wave & 1) * 32 + rt * 16 + (lane & 15);
        if (grow < n) {
#pragma unroll
            for (int ct = 0; ct < 4; ct++) {
                int col = (wave >> 1) * 64 + ct * 16 + (lane >> 4) * 4;
                union { unsigned short s[4]; uint2 v; } o;
                o.s[0] = f2bf(acc[rt][ct][0]);
                o.s[1] = f2bf(acc[rt][ct][1]);
                o.s[2] = f2bf(acc[rt][ct][2]);
                o.s[3] = f2bf(acc[rt][ct][3]);
                *(uint2*)&h[(size_t)grow * OUT_DIM + col] = o.v;
            }
        }
    }
#undef LOAD_REGS
#undef WRITE_LDS
}

// ---------------------------------------------------------------------------
// Kernel 7: CSR-SpMM + norm + bias. One wave per row, 8-edge unroll.
// ---------------------------------------------------------------------------
__global__ __launch_bounds__(256) void spmm_csr_kernel(
    const int* __restrict__ row_start, const int* __restrict__ row_end,
    const int* __restrict__ csr_src, const unsigned short* __restrict__ h,
    const float* __restrict__ bias, float* __restrict__ out_feat, int n)
{
    const int lane = threadIdx.x & 63;
    const int c2 = lane * 2;
    const float bi0 = bias[c2], bi1 = bias[c2 + 1];
    const int wave0 = blockIdx.x * 4 + (threadIdx.x >> 6);
    const int nwaves = gridDim.x * 4;

    for (int row = wave0; row < n; row += nwaves) {
        const int rs = row_start[row];
        const int re = row_end[row];

        float aL[4] = {0.f, 0.f, 0.f, 0.f};
        float aH[4] = {0.f, 0.f, 0.f, 0.f};
        int j = rs;
        for (; j + 7 < re; j += 8) {
            int s[8];
#pragma unroll
            for (int t = 0; t < 8; t++) s[t] = csr_src[j + t];
            unsigned v[8];
#pragma unroll
            for (int t = 0; t < 8; t++)
                v[t] = *(const unsigned*)&h[(size_t)s[t] * OUT_DIM + c2];
#pragma unroll
            for (int t = 0; t < 8; t++) {
                union { unsigned u; float f; } x, y;
                x.u = v[t] << 16;
                y.u = v[t] & 0xffff0000u;
                aL[t & 3] += x.f;
                aH[t & 3] += y.f;
            }
        }
        for (; j < re; ++j) {
            int s0 = csr_src[j];
            unsigned v0 = *(const unsigned*)&h[(size_t)s0 * OUT_DIM + c2];
            union { unsigned u; float f; } x, y;
            x.u = v0 << 16;
            y.u = v0 & 0xffff0000u;
            aL[0] += x.f;
            aH[0] += y.f;
        }

        const float nd = rsqrtf(fmaxf((float)(re - rs), 1.0f));
        const float f0 = ((aL[0] + aL[1]) + (aL[2] + aL[3])) * nd + bi0;
        const float f1 = ((aH[0] + aH[1]) + (aH[2] + aH[3])) * nd + bi1;
        *(float2*)&out_feat[(size_t)row * OUT_DIM + c2] = make_float2(f0, f1);
    }
}

// ---------------------------------------------------------------------------
// Kernel 8: logits = F @ mlp_w + mlp_b via MFMA.
// ---------------------------------------------------------------------------
__global__ __launch_bounds__(256) void mlp_mfma_kernel(
    const float* __restrict__ F, const float* __restrict__ mlp_w,
    const float* __restrict__ mlp_b, float* __restrict__ out_logits, int n)
{
    __shared__ unsigned short A_lds[48 * 136];
    __shared__ float s_mlpb[48];

    const int tid = threadIdx.x;
    for (int i = tid; i < 48 * 128; i += 256) {
        int cls = i >> 7, k = i & 127;
        A_lds[cls * 136 + k] =
            (cls < N_CLS) ? f2bf(mlp_w[(size_t)k * N_CLS + cls]) : (unsigned short)0;
    }
    if (tid < 48) s_mlpb[tid] = (tid < N_CLS) ? mlp_b[tid] : 0.f;
    __syncthreads();

    const int wave = tid >> 6, lane = tid & 63;
    const int r = lane & 15, koff = (lane >> 4) * 8;
    const int row = blockIdx.x * 64 + wave * 16 + r;
    const int rowc = (row < n) ? row : (n - 1);
    const float* fp = F + (size_t)rowc * OUT_DIM + koff;

    floatx4 acc[3];
#pragma unroll
    for (int ct = 0; ct < 3; ct++) acc[ct] = (floatx4){0.f, 0.f, 0.f, 0.f};

#pragma unroll
    for (int kk = 0; kk < 4; kk++) {
        floatx4 v0 = *(const floatx4*)(fp + kk * 32);
        floatx4 v1 = *(const floatx4*)(fp + kk * 32 + 4);
        union { unsigned short s[8]; short8 v; } bfr;
#pragma unroll
        for (int i = 0; i < 4; i++) {
            bfr.s[i]     = f2bf(v0[i]);
            bfr.s[4 + i] = f2bf(v1[i]);
        }
#pragma unroll
        for (int ct = 0; ct < 3; ct++) {
            short8 af = *(const short8*)&A_lds[(ct * 16 + r) * 136 + kk * 32 + koff];
            acc[ct] = __builtin_amdgcn_mfma_f32_16x16x32_bf16(af, bfr.v, acc[ct], 0, 0, 0);
        }
    }

    if (row < n) {
#pragma unroll
        for (int ct = 0; ct < 3; ct++)
#pragma unroll
            for (int i = 0; i < 4; i++) {
                int cls = ct * 16 + (lane >> 4) * 4 + i;
                if (cls < N_CLS)
                    out_logits[(size_t)row * N_CLS + cls] = acc[ct][i] + s_mlpb[cls];
            }
    }
}

// ---------------------------------------------------------------------------
extern "C" void kernel_launch(void* const* d_in, const int* in_sizes, int n_in,
                              void* d_out, int out_size, void* d_ws, size_t ws_size,
                              hipStream_t stream) {
    const int*   nodes = (const int*)d_in[0];
    const int*   src   = (const int*)d_in[1];
    const int*   dst   = (const int*)d_in[2];
    const float* emb   = (const float*)d_in[3];
    const float* W     = (const float*)d_in[4];
    const float* b     = (const float*)d_in[5];
    const float* mlp_w = (const float*)d_in[6];
    const float* mlp_b = (const float*)d_in[7];

    const int n  = in_sizes[0];   // 50000
    const int ne = in_sizes[1];   // 800000

    // ws layout (ints): cnt_out[n] | cnt_in[n] | row_start[n+8] | csr_src[ne]
    //   | partial_out[NE_CH*n] | partial_in[NE_CH*n] | bf16 Wt | bf16 h[n*128]
    int* cnt_out     = (int*)d_ws;
    int* cnt_in      = cnt_out + n;
    int* row_start   = cnt_in + n;           // n+1 used, padded to n+8
    int* csr_src     = row_start + n + 8;
    int* partial_out = csr_src + ne;
    int* partial_in  = partial_out + (size_t)NE_CH * n;
    size_t off = ((size_t)(3 * n + 8) + (size_t)ne + 2 * (size_t)NE_CH * n) * sizeof(int);
    off = (off + 15) & ~(size_t)15;
    unsigned short* Wt = (unsigned short*)((char*)d_ws + off);
    off += (size_t)IN_DIM * OUT_DIM * sizeof(unsigned short);
    off = (off + 15) & ~(size_t)15;
    unsigned short* h = (unsigned short*)((char*)d_ws + off);

    float* out_feat   = (float*)d_out;                    // n*128
    float* out_logits = out_feat + (size_t)n * OUT_DIM;   // n*40

    const int ns = (n + SLICE - 1) / SLICE;               // 7
    const int chunk = (((ne + NE_CH - 1) / NE_CH) + 3) & ~3;

    hist_kernel<<<ns * NE_CH, 256, 0, stream>>>(
        src, dst, partial_out, partial_in, ne, n, chunk);
    reduce_kernel<<<((n >> 2) + 255) / 256, 256, 0, stream>>>(
        partial_out, partial_in, cnt_out, cnt_in, n);
    scan_kernel<<<1, 1024, 0, stream>>>(cnt_in, row_start, n);
    scatter_lds_kernel<<<ns * NE_CH, 256, 0, stream>>>(
        src, dst, row_start, partial_in, csr_src, ne, n, chunk);
    wconv_kernel<<<(IN_DIM * OUT_DIM + 255) / 256, 256, 0, stream>>>(W, Wt);
    gemm1_mfma_kernel<<<(n + 63) / 64, 256, 0, stream>>>(nodes, emb, Wt, cnt_out, h, n);
    spmm_csr_kernel<<<(n + 3) / 4, 256, 0, stream>>>(
        row_start, row_start + 1, csr_src, h, b, out_feat, n);
    mlp_mfma_kernel<<<(n + 63) / 64, 256, 0, stream>>>(
        out_feat, mlp_w, mlp_b, out_logits, n);
}

// Round 6
// 150.380 us; speedup vs baseline: 10.4071x; 1.0469x over previous
//
#include <hip/hip_runtime.h>

#define IN_DIM 256
#define OUT_DIM 128
#define N_CLS 40

#define SLICE 8192     // nodes per LDS histogram slice (2 x 32 KB LDS)
#define NE_CH 20       // edge chunks

typedef __attribute__((ext_vector_type(8))) short short8;
typedef __attribute__((ext_vector_type(4))) float floatx4;

static __device__ __forceinline__ unsigned short f2bf(float f) {
    union { float f; unsigned u; } v; v.f = f;
    unsigned r = v.u + 0x7FFF + ((v.u >> 16) & 1);
    return (unsigned short)(r >> 16);
}

// ---------------------------------------------------------------------------
// Kernel 1: LDS-privatized histograms -> partial_out/partial_in [NE_CH][n],
// PLUS (merged) Wt[col][k] = bf16(W[k][col]) in trailing blocks.
// ---------------------------------------------------------------------------
__global__ __launch_bounds__(256) void hist_wconv_kernel(
    const int* __restrict__ src, const int* __restrict__ dst,
    int* __restrict__ partial_out, int* __restrict__ partial_in,
    const float* __restrict__ W, unsigned short* __restrict__ Wt,
    int ne, int n, int chunk, int nbh)
{
    __shared__ __align__(16) int lh_out[SLICE];
    __shared__ __align__(16) int lh_in[SLICE];

    const int tid = threadIdx.x;

    if (blockIdx.x >= nbh) {           // wconv part
        int t = (blockIdx.x - nbh) * 256 + tid;
        if (t < IN_DIM * OUT_DIM) {
            int k = t >> 7, c = t & 127;
            Wt[c * IN_DIM + k] = f2bf(W[t]);
        }
        return;
    }

    const int s = blockIdx.x / NE_CH;
    const int e = blockIdx.x % NE_CH;
    const int lo = s * SLICE;
    const int hi = min(lo + SLICE, n);

    for (int i = tid; i < SLICE; i += 256) { lh_out[i] = 0; lh_in[i] = 0; }
    __syncthreads();

    const int start = e * chunk;
    const int end = min(start + chunk, ne);
    const int cnt4 = (end - start) >> 2;
    const int4* s4 = (const int4*)(src + start);
    const int4* d4 = (const int4*)(dst + start);
    for (int k = tid; k < cnt4; k += 256) {
        int4 sv = s4[k];
        int4 dv = d4[k];
        unsigned q;
        q = (unsigned)(sv.x - lo); if (q < SLICE) atomicAdd(&lh_out[q], 1);
        q = (unsigned)(sv.y - lo); if (q < SLICE) atomicAdd(&lh_out[q], 1);
        q = (unsigned)(sv.z - lo); if (q < SLICE) atomicAdd(&lh_out[q], 1);
        q = (unsigned)(sv.w - lo); if (q < SLICE) atomicAdd(&lh_out[q], 1);
        q = (unsigned)(dv.x - lo); if (q < SLICE) atomicAdd(&lh_in[q], 1);
        q = (unsigned)(dv.y - lo); if (q < SLICE) atomicAdd(&lh_in[q], 1);
        q = (unsigned)(dv.z - lo); if (q < SLICE) atomicAdd(&lh_in[q], 1);
        q = (unsigned)(dv.w - lo); if (q < SLICE) atomicAdd(&lh_in[q], 1);
    }
    for (int t = start + (cnt4 << 2) + tid; t < end; t += 256) {
        unsigned q;
        q = (unsigned)(src[t] - lo); if (q < SLICE) atomicAdd(&lh_out[q], 1);
        q = (unsigned)(dst[t] - lo); if (q < SLICE) atomicAdd(&lh_in[q], 1);
    }
    __syncthreads();

    const int cnt = hi - lo;
    const int c4 = cnt >> 2;
    int4* po = (int4*)(partial_out + (size_t)e * n + lo);
    int4* pi = (int4*)(partial_in + (size_t)e * n + lo);
    for (int i = tid; i < c4; i += 256) {
        po[i] = ((const int4*)lh_out)[i];
        pi[i] = ((const int4*)lh_in)[i];
    }
    for (int i = (c4 << 2) + tid; i < cnt; i += 256) {
        partial_out[(size_t)e * n + lo + i] = lh_out[i];
        partial_in[(size_t)e * n + lo + i] = lh_in[i];
    }
}

// ---------------------------------------------------------------------------
// Kernel 2: reduce partials -> cnt_out, cnt_in; partial_in -> exclusive
// prefix along the chunk axis (for atomic-free scatter).
// ---------------------------------------------------------------------------
__global__ __launch_bounds__(256) void reduce_kernel(
    int* __restrict__ partial_out, int* __restrict__ partial_in,
    int* __restrict__ cnt_out, int* __restrict__ cnt_in, int n)
{
    const int g = blockIdx.x * 256 + threadIdx.x;
    const int ng4 = n >> 2;
    if (g < ng4) {
        const size_t base = (size_t)g * 4;
        int4 sum = make_int4(0, 0, 0, 0);
#pragma unroll
        for (int e = 0; e < NE_CH; e++) {
            int4 v = *(const int4*)(partial_out + (size_t)e * n + base);
            sum.x += v.x; sum.y += v.y; sum.z += v.z; sum.w += v.w;
        }
        *(int4*)(cnt_out + base) = sum;

        int4 run = make_int4(0, 0, 0, 0);
#pragma unroll
        for (int e = 0; e < NE_CH; e++) {
            int* p = partial_in + (size_t)e * n + base;
            int4 v = *(const int4*)p;
            *(int4*)p = run;
            run.x += v.x; run.y += v.y; run.z += v.z; run.w += v.w;
        }
        *(int4*)(cnt_in + base) = run;
    }
    const int t = (ng4 << 2) + g;
    if (t < n) {
        int sum = 0;
#pragma unroll
        for (int e = 0; e < NE_CH; e++) sum += partial_out[(size_t)e * n + t];
        cnt_out[t] = sum;
        int run = 0;
#pragma unroll
        for (int e = 0; e < NE_CH; e++) {
            int v = partial_in[(size_t)e * n + t];
            partial_in[(size_t)e * n + t] = run;
            run += v;
        }
        cnt_in[t] = run;
    }
}

// ---------------------------------------------------------------------------
// Kernel 3: single-block exclusive scan of cnt_in -> row_start[n+1]
// ---------------------------------------------------------------------------
__global__ __launch_bounds__(1024) void scan_kernel(
    const int* __restrict__ cnt, int* __restrict__ row_start, int n)
{
    __shared__ int wsum[16];
    __shared__ int carry_s;
    const int tid = threadIdx.x;
    const int lane = tid & 63, wid = tid >> 6;
    if (tid == 0) carry_s = 0;
    __syncthreads();

    for (int chunk = 0; chunk < n; chunk += 8192) {
        int base = chunk + tid * 8;
        int v[8];
        if (base + 8 <= n) {
            int4 a = *(const int4*)&cnt[base];
            int4 b = *(const int4*)&cnt[base + 4];
            v[0]=a.x; v[1]=a.y; v[2]=a.z; v[3]=a.w;
            v[4]=b.x; v[5]=b.y; v[6]=b.z; v[7]=b.w;
        } else {
#pragma unroll
            for (int t = 0; t < 8; t++) v[t] = (base + t < n) ? cnt[base + t] : 0;
        }
        int tsum = 0;
#pragma unroll
        for (int t = 0; t < 8; t++) tsum += v[t];

        int incl = tsum;
#pragma unroll
        for (int off = 1; off < 64; off <<= 1) {
            int q = __shfl_up(incl, (unsigned)off, 64);
            if (lane >= off) incl += q;
        }
        if (lane == 63) wsum[wid] = incl;
        __syncthreads();
        int woff = 0;
        for (int w = 0; w < wid; ++w) woff += wsum[w];
        int carry = carry_s;
        int run = carry + woff + (incl - tsum);
        if (base + 8 <= n) {
            int o[8];
#pragma unroll
            for (int t = 0; t < 8; t++) { o[t] = run; run += v[t]; }
            int4 r0, r1;
            r0.x=o[0]; r0.y=o[1]; r0.z=o[2]; r0.w=o[3];
            r1.x=o[4]; r1.y=o[5]; r1.z=o[6]; r1.w=o[7];
            *(int4*)&row_start[base]     = r0;
            *(int4*)&row_start[base + 4] = r1;
        } else {
#pragma unroll
            for (int t = 0; t < 8; t++) {
                if (base + t < n) row_start[base + t] = run;
                run += v[t];
            }
        }
        __syncthreads();
        if (tid == 1023) carry_s = carry + woff + incl;
        __syncthreads();
    }
    if (tid == 0) row_start[n] = carry_s;
}

// ---------------------------------------------------------------------------
// Kernel 4: scatter with LDS cursors (no global atomics).
// ---------------------------------------------------------------------------
__global__ __launch_bounds__(256) void scatter_lds_kernel(
    const int* __restrict__ src, const int* __restrict__ dst,
    const int* __restrict__ row_start, const int* __restrict__ prefix_in,
    int* __restrict__ csr_src, int ne, int n, int chunk)
{
    __shared__ __align__(16) int cur[SLICE];

    const int tid = threadIdx.x;
    const int s = blockIdx.x / NE_CH;
    const int e = blockIdx.x % NE_CH;
    const int lo = s * SLICE;
    const int hi = min(lo + SLICE, n);
    const int cnt = hi - lo;

    const int c4 = cnt >> 2;
    for (int i = tid; i < c4; i += 256) {
        int4 rs = *(const int4*)(row_start + lo + i * 4);
        int4 pf = *(const int4*)(prefix_in + (size_t)e * n + lo + i * 4);
        rs.x += pf.x; rs.y += pf.y; rs.z += pf.z; rs.w += pf.w;
        ((int4*)cur)[i] = rs;
    }
    for (int i = (c4 << 2) + tid; i < cnt; i += 256)
        cur[i] = row_start[lo + i] + prefix_in[(size_t)e * n + lo + i];
    __syncthreads();

    const int start = e * chunk;
    const int end = min(start + chunk, ne);
    const int cnt4e = (end - start) >> 2;
    const int4* s4 = (const int4*)(src + start);
    const int4* d4 = (const int4*)(dst + start);
    for (int k = tid; k < cnt4e; k += 256) {
        int4 sv = s4[k];
        int4 dv = d4[k];
        unsigned q;
        q = (unsigned)(dv.x - lo); if (q < SLICE) csr_src[atomicAdd(&cur[q], 1)] = sv.x;
        q = (unsigned)(dv.y - lo); if (q < SLICE) csr_src[atomicAdd(&cur[q], 1)] = sv.y;
        q = (unsigned)(dv.z - lo); if (q < SLICE) csr_src[atomicAdd(&cur[q], 1)] = sv.z;
        q = (unsigned)(dv.w - lo); if (q < SLICE) csr_src[atomicAdd(&cur[q], 1)] = sv.w;
    }
    for (int t = start + (cnt4e << 2) + tid; t < end; t += 256) {
        unsigned q = (unsigned)(dst[t] - lo);
        if (q < SLICE) csr_src[atomicAdd(&cur[q], 1)] = src[t];
    }
}

// ---------------------------------------------------------------------------
// Kernel 5: h = bf16( (emb[nodes]) @ W ) * rsqrt(deg) via bf16 MFMA;
// row-scale applied in f32 EPILOGUE (diag(s)·(F@W) == (diag(s)·F)@W).
// ---------------------------------------------------------------------------
__global__ __launch_bounds__(256) void gemm1_mfma_kernel(
    const int* __restrict__ nodes, const float* __restrict__ emb,
    const unsigned short* __restrict__ Wt, const int* __restrict__ cnt_out,
    unsigned short* __restrict__ h, int n)
{
    __shared__ unsigned short A_lds[64 * 40];
    __shared__ unsigned short B_lds[128 * 40];
    __shared__ int   snode[64];
    __shared__ float sscale[64];

    const int tid = threadIdx.x;
    const int m0  = blockIdx.x * 64;

    if (tid < 64) {
        int gr = m0 + tid;
        snode[tid]  = (gr < n) ? nodes[gr] : 0;
        sscale[tid] = (gr < n) ? rsqrtf(fmaxf((float)cnt_out[gr], 1.0f)) : 0.0f;
    }
    __syncthreads();

    const int arow = tid >> 2, aq = tid & 3;
    const int bcol = tid >> 1, bh = tid & 1;
    const float* aptr = emb + (size_t)snode[arow] * IN_DIM + aq * 8;
    const unsigned short* bptr = Wt + bcol * IN_DIM + bh * 16;

    float    ar[8];
    unsigned bw[8];

#define LOAD_REGS(KK) do {                                          \
        const floatx4 v0 = *(const floatx4*)(aptr + (KK) * 32);     \
        const floatx4 v1 = *(const floatx4*)(aptr + (KK) * 32 + 4); \
        ar[0]=v0[0]; ar[1]=v0[1]; ar[2]=v0[2]; ar[3]=v0[3];         \
        ar[4]=v1[0]; ar[5]=v1[1]; ar[6]=v1[2]; ar[7]=v1[3];         \
        const uint4 w0 = *(const uint4*)(bptr + (KK) * 32);         \
        const uint4 w1 = *(const uint4*)(bptr + (KK) * 32 + 8);     \
        bw[0]=w0.x; bw[1]=w0.y; bw[2]=w0.z; bw[3]=w0.w;             \
        bw[4]=w1.x; bw[5]=w1.y; bw[6]=w1.z; bw[7]=w1.w;             \
    } while (0)

#define WRITE_LDS() do {                                            \
        union { unsigned short s[8]; uint4 v; } ua;                 \
        _Pragma("unroll")                                           \
        for (int i = 0; i < 8; i++) ua.s[i] = f2bf(ar[i]);          \
        *(uint4*)&A_lds[arow * 40 + aq * 8] = ua.v;                 \
        uint4 b0, b1;                                               \
        b0.x=bw[0]; b0.y=bw[1]; b0.z=bw[2]; b0.w=bw[3];             \
        b1.x=bw[4]; b1.y=bw[5]; b1.z=bw[6]; b1.w=bw[7];             \
        *(uint4*)&B_lds[bcol * 40 + bh * 16]     = b0;              \
        *(uint4*)&B_lds[bcol * 40 + bh * 16 + 8] = b1;              \
    } while (0)

    const int wave = tid >> 6, lane = tid & 63;
    const int rbase = (wave & 1) * 32 + (lane & 15);
    const int cbase = (wave >> 1) * 64 + (lane & 15);
    const int koff  = (lane >> 4) * 8;

    floatx4 acc[2][4];
#pragma unroll
    for (int i = 0; i < 2; i++)
#pragma unroll
        for (int j = 0; j < 4; j++) acc[i][j] = (floatx4){0.f, 0.f, 0.f, 0.f};

    LOAD_REGS(0);
    WRITE_LDS();

    for (int kk = 0; kk < 8; ++kk) {
        if (kk < 7) LOAD_REGS(kk + 1);
        __syncthreads();
        short8 af0 = *(const short8*)&A_lds[rbase * 40 + koff];
        short8 af1 = *(const short8*)&A_lds[(rbase + 16) * 40 + koff];
        short8 bf[4];
#pragma unroll
        for (int ct = 0; ct < 4; ct++)
            bf[ct] = *(const short8*)&B_lds[(cbase + ct * 16) * 40 + koff];
#pragma unroll
        for (int ct = 0; ct < 4; ct++) {
            acc[0][ct] = __builtin_amdgcn_mfma_f32_16x16x32_bf16(bf[ct], af0, acc[0][ct], 0, 0, 0);
            acc[1][ct] = __builtin_amdgcn_mfma_f32_16x16x32_bf16(bf[ct], af1, acc[1][ct], 0, 0, 0);
        }
        __syncthreads();
        if (kk < 7) WRITE_LDS();
    }

#pragma unroll
    for (int rt = 0; rt < 2; rt++) {
        int lrow = (wave & 1) * 32 + rt * 16 + (lane & 15);
        int grow = m0 + lrow;
        float sc = sscale[lrow];
        if (grow < n) {
#pragma unroll
            for (int ct = 0; ct < 4; ct++) {
                int col = (wave >> 1) * 64 + ct * 16 + (lane >> 4) * 4;
                union { unsigned short s[4]; uint2 v; } o;
                o.s[0] = f2bf(acc[rt][ct][0] * sc);
                o.s[1] = f2bf(acc[rt][ct][1] * sc);
                o.s[2] = f2bf(acc[rt][ct][2] * sc);
                o.s[3] = f2bf(acc[rt][ct][3] * sc);
                *(uint2*)&h[(size_t)grow * OUT_DIM + col] = o.v;
            }
        }
    }
#undef LOAD_REGS
#undef WRITE_LDS
}

// ---------------------------------------------------------------------------
// Kernel 6: CSR-SpMM + norm + bias. One wave per row.
// All (≤64) row indices loaded in ONE coalesced lane-parallel load, then
// shfl-broadcast -> all h-row gathers issue back-to-back (latency hiding).
// ---------------------------------------------------------------------------
__global__ __launch_bounds__(256) void spmm_csr_kernel(
    const int* __restrict__ row_start, const int* __restrict__ csr_src,
    const unsigned short* __restrict__ h, const float* __restrict__ bias,
    float* __restrict__ out_feat, int n)
{
    const int lane = threadIdx.x & 63;
    const int c2 = lane * 2;
    const int row = blockIdx.x * 4 + (threadIdx.x >> 6);
    if (row >= n) return;

    const int rs = row_start[row];
    const int re = row_start[row + 1];
    const int deg = re - rs;

    float aL[4] = {0.f, 0.f, 0.f, 0.f};
    float aH[4] = {0.f, 0.f, 0.f, 0.f};

    for (int base = 0; base < deg; base += 64) {
        const int cnt = min(deg - base, 64);
        int idx = (lane < cnt) ? csr_src[rs + base + lane] : 0;
        int t = 0;
        for (; t + 7 < cnt; t += 8) {
            int s[8];
#pragma unroll
            for (int u = 0; u < 8; u++) s[u] = __shfl(idx, t + u, 64);
            unsigned v[8];
#pragma unroll
            for (int u = 0; u < 8; u++)
                v[u] = *(const unsigned*)&h[(size_t)s[u] * OUT_DIM + c2];
#pragma unroll
            for (int u = 0; u < 8; u++) {
                union { unsigned uu; float f; } x, y;
                x.uu = v[u] << 16;
                y.uu = v[u] & 0xffff0000u;
                aL[u & 3] += x.f;
                aH[u & 3] += y.f;
            }
        }
        for (; t + 3 < cnt; t += 4) {
            int s[4];
#pragma unroll
            for (int u = 0; u < 4; u++) s[u] = __shfl(idx, t + u, 64);
            unsigned v[4];
#pragma unroll
            for (int u = 0; u < 4; u++)
                v[u] = *(const unsigned*)&h[(size_t)s[u] * OUT_DIM + c2];
#pragma unroll
            for (int u = 0; u < 4; u++) {
                union { unsigned uu; float f; } x, y;
                x.uu = v[u] << 16;
                y.uu = v[u] & 0xffff0000u;
                aL[u] += x.f;
                aH[u] += y.f;
            }
        }
        for (; t < cnt; ++t) {
            int s0 = __shfl(idx, t, 64);
            unsigned v0 = *(const unsigned*)&h[(size_t)s0 * OUT_DIM + c2];
            union { unsigned uu; float f; } x, y;
            x.uu = v0 << 16;
            y.uu = v0 & 0xffff0000u;
            aL[0] += x.f;
            aH[0] += y.f;
        }
    }

    const float nd = rsqrtf(fmaxf((float)deg, 1.0f));
    const float f0 = ((aL[0] + aL[1]) + (aL[2] + aL[3])) * nd + bias[c2];
    const float f1 = ((aH[0] + aH[1]) + (aH[2] + aH[3])) * nd + bias[c2 + 1];
    *(float2*)&out_feat[(size_t)row * OUT_DIM + c2] = make_float2(f0, f1);
}

// ---------------------------------------------------------------------------
// Kernel 7: logits = F @ mlp_w + mlp_b via MFMA.
// ---------------------------------------------------------------------------
__global__ __launch_bounds__(256) void mlp_mfma_kernel(
    const float* __restrict__ F, const float* __restrict__ mlp_w,
    const float* __restrict__ mlp_b, float* __restrict__ out_logits, int n)
{
    __shared__ unsigned short A_lds[48 * 136];
    __shared__ float s_mlpb[48];

    const int tid = threadIdx.x;
    for (int i = tid; i < 48 * 128; i += 256) {
        int cls = i >> 7, k = i & 127;
        A_lds[cls * 136 + k] =
            (cls < N_CLS) ? f2bf(mlp_w[(size_t)k * N_CLS + cls]) : (unsigned short)0;
    }
    if (tid < 48) s_mlpb[tid] = (tid < N_CLS) ? mlp_b[tid] : 0.f;
    __syncthreads();

    const int wave = tid >> 6, lane = tid & 63;
    const int r = lane & 15, koff = (lane >> 4) * 8;
    const int row = blockIdx.x * 64 + wave * 16 + r;
    const int rowc = (row < n) ? row : (n - 1);
    const float* fp = F + (size_t)rowc * OUT_DIM + koff;

    floatx4 acc[3];
#pragma unroll
    for (int ct = 0; ct < 3; ct++) acc[ct] = (floatx4){0.f, 0.f, 0.f, 0.f};

#pragma unroll
    for (int kk = 0; kk < 4; kk++) {
        floatx4 v0 = *(const floatx4*)(fp + kk * 32);
        floatx4 v1 = *(const floatx4*)(fp + kk * 32 + 4);
        union { unsigned short s[8]; short8 v; } bfr;
#pragma unroll
        for (int i = 0; i < 4; i++) {
            bfr.s[i]     = f2bf(v0[i]);
            bfr.s[4 + i] = f2bf(v1[i]);
        }
#pragma unroll
        for (int ct = 0; ct < 3; ct++) {
            short8 af = *(const short8*)&A_lds[(ct * 16 + r) * 136 + kk * 32 + koff];
            acc[ct] = __builtin_amdgcn_mfma_f32_16x16x32_bf16(af, bfr.v, acc[ct], 0, 0, 0);
        }
    }

    if (row < n) {
#pragma unroll
        for (int ct = 0; ct < 3; ct++)
#pragma unroll
            for (int i = 0; i < 4; i++) {
                int cls = ct * 16 + (lane >> 4) * 4 + i;
                if (cls < N_CLS)
                    out_logits[(size_t)row * N_CLS + cls] = acc[ct][i] + s_mlpb[cls];
            }
    }
}

// ---------------------------------------------------------------------------
extern "C" void kernel_launch(void* const* d_in, const int* in_sizes, int n_in,
                              void* d_out, int out_size, void* d_ws, size_t ws_size,
                              hipStream_t stream) {
    const int*   nodes = (const int*)d_in[0];
    const int*   src   = (const int*)d_in[1];
    const int*   dst   = (const int*)d_in[2];
    const float* emb   = (const float*)d_in[3];
    const float* W     = (const float*)d_in[4];
    const float* b     = (const float*)d_in[5];
    const float* mlp_w = (const float*)d_in[6];
    const float* mlp_b = (const float*)d_in[7];

    const int n  = in_sizes[0];   // 50000
    const int ne = in_sizes[1];   // 800000

    // ws layout (ints): cnt_out[n] | cnt_in[n] | row_start[n+8] | csr_src[ne]
    //   | partial_out[NE_CH*n] | partial_in[NE_CH*n] | bf16 Wt | bf16 h[n*128]
    int* cnt_out     = (int*)d_ws;
    int* cnt_in      = cnt_out + n;
    int* row_start   = cnt_in + n;
    int* csr_src     = row_start + n + 8;
    int* partial_out = csr_src + ne;
    int* partial_in  = partial_out + (size_t)NE_CH * n;
    size_t off = ((size_t)(3 * n + 8) + (size_t)ne + 2 * (size_t)NE_CH * n) * sizeof(int);
    off = (off + 15) & ~(size_t)15;
    unsigned short* Wt = (unsigned short*)((char*)d_ws + off);
    off += (size_t)IN_DIM * OUT_DIM * sizeof(unsigned short);
    off = (off + 15) & ~(size_t)15;
    unsigned short* h = (unsigned short*)((char*)d_ws + off);

    float* out_feat   = (float*)d_out;                    // n*128
    float* out_logits = out_feat + (size_t)n * OUT_DIM;   // n*40

    const int ns = (n + SLICE - 1) / SLICE;               // 7
    const int chunk = (((ne + NE_CH - 1) / NE_CH) + 3) & ~3;
    const int nbh = ns * NE_CH;                           // 140 hist blocks
    const int nbw = (IN_DIM * OUT_DIM + 255) / 256;       // 128 wconv blocks

    hist_wconv_kernel<<<nbh + nbw, 256, 0, stream>>>(
        src, dst, partial_out, partial_in, W, Wt, ne, n, chunk, nbh);
    reduce_kernel<<<((n >> 2) + 255) / 256, 256, 0, stream>>>(
        partial_out, partial_in, cnt_out, cnt_in, n);
    scan_kernel<<<1, 1024, 0, stream>>>(cnt_in, row_start, n);
    scatter_lds_kernel<<<nbh, 256, 0, stream>>>(
        src, dst, row_start, partial_in, csr_src, ne, n, chunk);
    gemm1_mfma_kernel<<<(n + 63) / 64, 256, 0, stream>>>(nodes, emb, Wt, cnt_out, h, n);
    spmm_csr_kernel<<<(n + 3) / 4, 256, 0, stream>>>(
        row_start, csr_src, h, b, out_feat, n);
    mlp_mfma_kernel<<<(n + 63) / 64, 256, 0, stream>>>(
        out_feat, mlp_w, mlp_b, out_logits, n);
}